// Round 15
// baseline (1847.294 us; speedup 1.0000x reference)
//
#include <hip/hip_runtime.h>

#define NB 16
#define NTOK 197
#define NPATCH 196
#define D 768
#define NH 12
#define HD 64
#define HOP 3072
#define TSTEPS 6
#define BETA_F 0.125f
#define PLD 208                 // Pt leading dim (fp16)
#define PBH (NTOK * PLD)        // 40976
#define NROWS (NB * NTOK)       // 3152
#define NPROWS (NB * NPATCH)    // 3136
#define AROWS 3200              // padded rows for MFMA A-side staging
#define DD (768 * 768)
#define DH (768 * 3072)
#define SZL ((long)NROWS * D)   // 2,420,736

typedef unsigned short u16;
typedef __attribute__((ext_vector_type(8))) _Float16 f16x8;
typedef __attribute__((ext_vector_type(4))) float f32x4;

#define FLAG_ACC 1
#define FLAG_RELU 2
#define FLAG_H16 4

__device__ __forceinline__ u16 f2h(float f) {
    union { _Float16 h; u16 u; } cv;
    cv.h = (_Float16)f;
    return cv.u;
}
__device__ __forceinline__ float h2f(u16 v) {
    union { _Float16 h; u16 u; } cv;
    cv.u = v;
    return (float)cv.h;
}

__device__ __forceinline__ void gld16(const void* g, void* l) {
    __builtin_amdgcn_global_load_lds((const __attribute__((address_space(1))) void*)g,
                                     (__attribute__((address_space(3))) void*)l, 16, 0, 0);
}

// ---------------- single-fp16 MFMA GEMM (out-projection) ----------------
__global__ __launch_bounds__(256) void gemm_h16(
    const u16* __restrict__ A, const u16* __restrict__ B,
    void* __restrict__ Cv, const float* __restrict__ bias,
    int M, int N, int K, int lda, int ldbt, int ldc, int flags,
    long sAz, long sBz, long sCz) {
    __shared__ __align__(16) u16 As[128 * 32];
    __shared__ __align__(16) u16 Bs[128 * 32];
    int zz = blockIdx.z;
    A += (long)zz * sAz;
    B += (long)zz * sBz;
    long czoff = (long)zz * sCz;
    int t = threadIdx.x;
    int w = t >> 6, lane = t & 63;
    int lr = lane & 15, lg = lane >> 4;
    int wr = w >> 1, wc = w & 1;
    long row0 = (long)blockIdx.y * 128, col0 = (long)blockIdx.x * 128;

    f32x4 acc[4][4];
#pragma unroll
    for (int i = 0; i < 4; i++)
#pragma unroll
        for (int j = 0; j < 4; j++) acc[i][j] = (f32x4){0.f, 0.f, 0.f, 0.f};

    int c0 = w * 64 + lane;
    int r0s = c0 >> 2, k0s = (((c0 & 3) ^ ((r0s >> 1) & 3)) << 3);
    int c1 = 256 + w * 64 + lane;
    int r1s = c1 >> 2, k1s = (((c1 & 3) ^ ((r1s >> 1) & 3)) << 3);

    for (int kt = 0; kt < K; kt += 32) {
        const u16* AB = A + row0 * lda + kt;
        const u16* BB = B + col0 * ldbt + kt;
        gld16(AB + (long)r0s * lda + k0s, (char*)As + (w * 64) * 16);
        gld16(AB + (long)r1s * lda + k1s, (char*)As + (256 + w * 64) * 16);
        gld16(BB + (long)r0s * ldbt + k0s, (char*)Bs + (w * 64) * 16);
        gld16(BB + (long)r1s * ldbt + k1s, (char*)Bs + (256 + w * 64) * 16);
        __syncthreads();
        f16x8 af[4], bf[4];
#pragma unroll
        for (int mi = 0; mi < 4; mi++) {
            int row = wr * 64 + mi * 16 + lr;
            af[mi] = *(const f16x8*)&As[row * 32 + ((lg ^ ((row >> 1) & 3)) << 3)];
        }
#pragma unroll
        for (int ni = 0; ni < 4; ni++) {
            int row = wc * 64 + ni * 16 + lr;
            bf[ni] = *(const f16x8*)&Bs[row * 32 + ((lg ^ ((row >> 1) & 3)) << 3)];
        }
#pragma unroll
        for (int mi = 0; mi < 4; mi++)
#pragma unroll
            for (int ni = 0; ni < 4; ni++)
                acc[mi][ni] = __builtin_amdgcn_mfma_f32_16x16x32_f16(af[mi], bf[ni], acc[mi][ni], 0, 0, 0);
        __syncthreads();
    }

    long mbase = row0 + wr * 64;
    long nbase = col0 + wc * 64;
#pragma unroll
    for (int mi = 0; mi < 4; mi++) {
#pragma unroll
        for (int r = 0; r < 4; r++) {
            long grow = mbase + mi * 16 + lg * 4 + r;
            if (grow >= M) continue;
#pragma unroll
            for (int ni = 0; ni < 4; ni++) {
                long gcol = nbase + ni * 16 + lr;
                float v = acc[mi][ni][r];
                if (bias) v += bias[gcol];
                if (flags & FLAG_RELU) v = fmaxf(v, 0.f);
                long idx = czoff + grow * ldc + gcol;
                if (flags & FLAG_ACC) ((float*)Cv)[idx] += v;
                else if (flags & FLAG_H16) ((u16*)Cv)[idx] = f2h(v);
                else ((float*)Cv)[idx] = v;
            }
        }
    }
}

// ---------------- fused projection: QK (f32 out) + Hopfield-1 (fp16+relu) ----------------
__global__ __launch_bounds__(256) void fused_proj(
    const u16* __restrict__ A,
    const u16* __restrict__ WQT, const u16* __restrict__ WKT, const u16* __restrict__ XIT,
    float* __restrict__ Qb, float* __restrict__ Kb, u16* __restrict__ HH) {
    __shared__ __align__(16) u16 As[128 * 32];
    __shared__ __align__(16) u16 Bs[128 * 32];
    int cx = blockIdx.x;
    const u16* B; int ldc; long col0; int mode;
    if (cx < 6)       { B = WQT; ldc = 768;  col0 = (long)cx * 128;        mode = 0; }
    else if (cx < 12) { B = WKT; ldc = 768;  col0 = (long)(cx - 6) * 128;  mode = 1; }
    else              { B = XIT; ldc = 3072; col0 = (long)(cx - 12) * 128; mode = 2; }
    int t = threadIdx.x;
    int w = t >> 6, lane = t & 63;
    int lr = lane & 15, lg = lane >> 4;
    int wr = w >> 1, wc = w & 1;
    long row0 = (long)blockIdx.y * 128;

    f32x4 acc[4][4];
#pragma unroll
    for (int i = 0; i < 4; i++)
#pragma unroll
        for (int j = 0; j < 4; j++) acc[i][j] = (f32x4){0.f, 0.f, 0.f, 0.f};

    int c0 = w * 64 + lane;
    int r0s = c0 >> 2, k0s = (((c0 & 3) ^ ((r0s >> 1) & 3)) << 3);
    int c1 = 256 + w * 64 + lane;
    int r1s = c1 >> 2, k1s = (((c1 & 3) ^ ((r1s >> 1) & 3)) << 3);

    for (int kt = 0; kt < 768; kt += 32) {
        const u16* AB = A + row0 * 768 + kt;
        const u16* BB = B + col0 * 768 + kt;
        gld16(AB + (long)r0s * 768 + k0s, (char*)As + (w * 64) * 16);
        gld16(AB + (long)r1s * 768 + k1s, (char*)As + (256 + w * 64) * 16);
        gld16(BB + (long)r0s * 768 + k0s, (char*)Bs + (w * 64) * 16);
        gld16(BB + (long)r1s * 768 + k1s, (char*)Bs + (256 + w * 64) * 16);
        __syncthreads();
        f16x8 af[4], bf[4];
#pragma unroll
        for (int mi = 0; mi < 4; mi++) {
            int row = wr * 64 + mi * 16 + lr;
            af[mi] = *(const f16x8*)&As[row * 32 + ((lg ^ ((row >> 1) & 3)) << 3)];
        }
#pragma unroll
        for (int ni = 0; ni < 4; ni++) {
            int row = wc * 64 + ni * 16 + lr;
            bf[ni] = *(const f16x8*)&Bs[row * 32 + ((lg ^ ((row >> 1) & 3)) << 3)];
        }
#pragma unroll
        for (int mi = 0; mi < 4; mi++)
#pragma unroll
            for (int ni = 0; ni < 4; ni++)
                acc[mi][ni] = __builtin_amdgcn_mfma_f32_16x16x32_f16(af[mi], bf[ni], acc[mi][ni], 0, 0, 0);
        __syncthreads();
    }

    long mbase = row0 + wr * 64;
    long nbase = col0 + wc * 64;
#pragma unroll
    for (int mi = 0; mi < 4; mi++) {
#pragma unroll
        for (int r = 0; r < 4; r++) {
            long grow = mbase + mi * 16 + lg * 4 + r;
            if (grow >= NROWS) continue;
#pragma unroll
            for (int ni = 0; ni < 4; ni++) {
                long gcol = nbase + ni * 16 + lr;
                float v = acc[mi][ni][r];
                long idx = grow * ldc + gcol;
                if (mode == 0)      Qb[idx] = v;
                else if (mode == 1) Kb[idx] = v;
                else                HH[idx] = f2h(fmaxf(v, 0.f));
            }
        }
    }
}

// ---------------- fused accumulate GEMM: 6 split-K partials -> fp16 slabs ----------------
__global__ __launch_bounds__(256) void gemm_h16_fused(
    const u16* __restrict__ G1, const u16* __restrict__ G2, const u16* __restrict__ HH,
    const u16* __restrict__ WQ, const u16* __restrict__ WK, const u16* __restrict__ XB,
    u16* __restrict__ part) {
    __shared__ __align__(16) u16 As[128 * 32];
    __shared__ __align__(16) u16 Bs[128 * 32];
    int zz = blockIdx.z;
    const u16* A; const u16* B; int lda; int K0;
    if (zz == 0)      { A = G1; B = WQ; lda = 768;  K0 = 0; }
    else if (zz == 1) { A = G2; B = WK; lda = 768;  K0 = 0; }
    else              { A = HH; B = XB; lda = 3072; K0 = (zz - 2) * 768; }
    u16* C = part + (long)zz * SZL;

    int t = threadIdx.x;
    int w = t >> 6, lane = t & 63;
    int lr = lane & 15, lg = lane >> 4;
    int wr = w >> 1, wc = w & 1;
    long row0 = (long)blockIdx.y * 128, col0 = (long)blockIdx.x * 128;

    f32x4 acc[4][4];
#pragma unroll
    for (int i = 0; i < 4; i++)
#pragma unroll
        for (int j = 0; j < 4; j++) acc[i][j] = (f32x4){0.f, 0.f, 0.f, 0.f};

    int c0 = w * 64 + lane;
    int r0s = c0 >> 2, k0s = (((c0 & 3) ^ ((r0s >> 1) & 3)) << 3);
    int c1 = 256 + w * 64 + lane;
    int r1s = c1 >> 2, k1s = (((c1 & 3) ^ ((r1s >> 1) & 3)) << 3);

    for (int kt = K0; kt < K0 + 768; kt += 32) {
        const u16* AB = A + row0 * lda + kt;
        const u16* BB = B + col0 * (long)lda + kt;
        gld16(AB + (long)r0s * lda + k0s, (char*)As + (w * 64) * 16);
        gld16(AB + (long)r1s * lda + k1s, (char*)As + (256 + w * 64) * 16);
        gld16(BB + (long)r0s * lda + k0s, (char*)Bs + (w * 64) * 16);
        gld16(BB + (long)r1s * lda + k1s, (char*)Bs + (256 + w * 64) * 16);
        __syncthreads();
        f16x8 af[4], bf[4];
#pragma unroll
        for (int mi = 0; mi < 4; mi++) {
            int row = wr * 64 + mi * 16 + lr;
            af[mi] = *(const f16x8*)&As[row * 32 + ((lg ^ ((row >> 1) & 3)) << 3)];
        }
#pragma unroll
        for (int ni = 0; ni < 4; ni++) {
            int row = wc * 64 + ni * 16 + lr;
            bf[ni] = *(const f16x8*)&Bs[row * 32 + ((lg ^ ((row >> 1) & 3)) << 3)];
        }
#pragma unroll
        for (int mi = 0; mi < 4; mi++)
#pragma unroll
            for (int ni = 0; ni < 4; ni++)
                acc[mi][ni] = __builtin_amdgcn_mfma_f32_16x16x32_f16(af[mi], bf[ni], acc[mi][ni], 0, 0, 0);
        __syncthreads();
    }

    long mbase = row0 + wr * 64;
    long nbase = col0 + wc * 64;
#pragma unroll
    for (int mi = 0; mi < 4; mi++) {
#pragma unroll
        for (int r = 0; r < 4; r++) {
            long grow = mbase + mi * 16 + lg * 4 + r;
            if (grow >= NROWS) continue;
#pragma unroll
            for (int ni = 0; ni < 4; ni++) {
                long gcol = nbase + ni * 16 + lr;
                C[grow * D + gcol] = f2h(acc[mi][ni][r]);
            }
        }
    }
}

// ---------------- fused reduce + layernorm: h (+= 6 fp16 slabs) -> LN -> fp16 ----------------
__global__ __launch_bounds__(256) void ln_fuse_kernel(
    float* __restrict__ X, u16* __restrict__ Yh16, const u16* __restrict__ part,
    const float* __restrict__ gamma, const float* __restrict__ beta,
    int compact, int doReduce, int writeBack) {
    int r = blockIdx.x;
    long xrow = compact ? ((long)(r / NPATCH) * NTOK + 1 + (r % NPATCH)) : (long)r;
    float* x = X + xrow * D;
    int t = threadIdx.x;
    float v[3];
    float s = 0.f, ss = 0.f;
#pragma unroll
    for (int i = 0; i < 3; i++) {
        int c = t + 256 * i;
        float val = x[c];
        if (doReduce) {
            long off = xrow * D + c;
            float p01 = h2f(part[off]) + h2f(part[SZL + off]);
            float p23 = h2f(part[2 * SZL + off]) + h2f(part[3 * SZL + off]);
            float p45 = h2f(part[4 * SZL + off]) + h2f(part[5 * SZL + off]);
            val += (p01 + p23) + p45;
            if (writeBack) x[c] = val;
        }
        v[i] = val;
        s += val;
        ss += val * val;
    }
    __shared__ float red[8];
    for (int off = 32; off; off >>= 1) {
        s += __shfl_down(s, off, 64);
        ss += __shfl_down(ss, off, 64);
    }
    int wid = t >> 6, lane = t & 63;
    if (lane == 0) { red[wid] = s; red[4 + wid] = ss; }
    __syncthreads();
    s = red[0] + red[1] + red[2] + red[3];
    ss = red[4] + red[5] + red[6] + red[7];
    float mu = s * (1.f / 768.f);
    float var = ss * (1.f / 768.f) - mu * mu;
    float inv = rsqrtf(var + 1e-5f);
#pragma unroll
    for (int i = 0; i < 3; i++) {
        int c = t + 256 * i;
        float yv = gamma[c] * (v[i] - mu) * inv + beta[c];
        Yh16[(long)r * D + c] = f2h(yv);
    }
}

// ---------------- parallel f32 attention softmax -> fp16 Pt ----------------
// ONE block per (b,h): stage K once (f32, 208x68 LDS), loop 13 m-tiles internally.
// Arithmetic (dot order, guards, stores) bit-identical to R14's version.
__global__ __launch_bounds__(256) void attn_p_kernel(const float* __restrict__ Q, const float* __restrict__ K,
                                                     u16* __restrict__ Pt) {
    __shared__ float Ks[208][68];
    int bh = blockIdx.x;
    int b = bh / NH, h = bh % NH;
    int t = threadIdx.x;
    const float* Kb = K + (long)b * NTOK * D + h * HD;
    for (int i = t; i < 208 * 16; i += 256) {
        int n = i >> 4, k4 = (i & 15) << 2;
        float4 v = make_float4(0.f, 0.f, 0.f, 0.f);
        if (n < NTOK) v = *(const float4*)(Kb + (long)n * D + k4);
        Ks[n][k4] = v.x; Ks[n][k4 + 1] = v.y; Ks[n][k4 + 2] = v.z; Ks[n][k4 + 3] = v.w;
    }
    __syncthreads();
    int ql = t >> 4, l16 = t & 15;
    u16* PtB = Pt + (long)bh * PBH;
    for (int mt = 0; mt < 13; mt++) {
        int m = mt * 16 + ql;
        int mr = m < NTOK ? m : NTOK - 1;
        const float* Qrow = Q + (long)(b * NTOK + mr) * D + h * HD;
        float q[64];
#pragma unroll
        for (int k = 0; k < 64; k += 4) {
            float4 v = *(const float4*)(Qrow + k);
            q[k] = v.x; q[k + 1] = v.y; q[k + 2] = v.z; q[k + 3] = v.w;
        }
        float s[13];
        float mx = -1e30f;
#pragma unroll
        for (int i = 0; i < 13; i++) {
            int n = i * 16 + l16;
            const float* kr = Ks[n < NTOK ? n : 0];
            float a0 = 0.f, a1 = 0.f, a2 = 0.f, a3 = 0.f;
#pragma unroll
            for (int k = 0; k < 64; k += 4) {
                a0 += kr[k] * q[k];
                a1 += kr[k + 1] * q[k + 1];
                a2 += kr[k + 2] * q[k + 2];
                a3 += kr[k + 3] * q[k + 3];
            }
            float sv = ((a0 + a1) + (a2 + a3)) * BETA_F;
            s[i] = (n < NTOK) ? sv : -1e30f;
            mx = fmaxf(mx, s[i]);
        }
        mx = fmaxf(mx, __shfl_xor(mx, 1, 64));
        mx = fmaxf(mx, __shfl_xor(mx, 2, 64));
        mx = fmaxf(mx, __shfl_xor(mx, 4, 64));
        mx = fmaxf(mx, __shfl_xor(mx, 8, 64));
        float ssum = 0.f;
#pragma unroll
        for (int i = 0; i < 13; i++) {
            float e = (s[i] > -1e29f) ? __expf(s[i] - mx) : 0.f;
            s[i] = e;
            ssum += e;
        }
        ssum += __shfl_xor(ssum, 1, 64);
        ssum += __shfl_xor(ssum, 2, 64);
        ssum += __shfl_xor(ssum, 4, 64);
        ssum += __shfl_xor(ssum, 8, 64);
        float inv = 1.f / ssum;
        if (m < NTOK) {
#pragma unroll
            for (int i = 0; i < 13; i++) {
                int n = i * 16 + l16;
                PtB[(long)m * PLD + n] = (n < NTOK) ? f2h(s[i] * inv) : (u16)0;
            }
        }
    }
}

// ---------------- attention grads: G1 (A normal) + G2 (A transposed), fp16 Pt in ----------------
__global__ __launch_bounds__(256) void attn_g_kernel(
    const u16* __restrict__ Pt, const float* __restrict__ Qb, const float* __restrict__ Kb,
    u16* __restrict__ G1, u16* __restrict__ G2) {
    __shared__ float As[16][68];
    __shared__ float Bs[16][68];
    int z = blockIdx.z;
    int which = z / 192, bh = z - which * 192;
    int b = bh / NH, h = bh % NH;
    const u16* A = Pt + (long)bh * PBH;
    const float* B = (which ? Qb : Kb) + (long)b * NTOK * D + h * HD;
    u16* G = which ? G2 : G1;

    int t = threadIdx.x;
    int tx = t & 15, ty = t >> 4;
    int row0 = blockIdx.y * 64;

    float acc[4][4] = {};

    for (int kt = 0; kt < NTOK; kt += 16) {
        if (which == 0) {
            int r = t >> 2, c4 = (t & 3) << 2;
            int gr = row0 + r, gk = kt + c4;
            float4 v = make_float4(0.f, 0.f, 0.f, 0.f);
            if (gr < NTOK) {
                ushort4 u = *(const ushort4*)(A + (long)gr * PLD + gk);
                v = make_float4(h2f(u.x), h2f(u.y), h2f(u.z), h2f(u.w));
            }
            As[c4 + 0][r] = v.x; As[c4 + 1][r] = v.y; As[c4 + 2][r] = v.z; As[c4 + 3][r] = v.w;
        } else {
            int rr = t >> 4, c4 = (t & 15) << 2;
            int gk = kt + rr, gc = row0 + c4;
            float4 v = make_float4(0.f, 0.f, 0.f, 0.f);
            if (gk < NTOK && gc + 3 < PLD) {
                ushort4 u = *(const ushort4*)(A + (long)gk * PLD + gc);
                v = make_float4(h2f(u.x), h2f(u.y), h2f(u.z), h2f(u.w));
            }
            As[rr][c4 + 0] = v.x; As[rr][c4 + 1] = v.y; As[rr][c4 + 2] = v.z; As[rr][c4 + 3] = v.w;
        }
        {
            int r = t >> 4, c4 = (t & 15) << 2;
            int gk = kt + r;
            float4 v = make_float4(0.f, 0.f, 0.f, 0.f);
            if (gk < NTOK) v = *(const float4*)(B + (long)gk * D + c4);
            Bs[r][c4 + 0] = v.x; Bs[r][c4 + 1] = v.y; Bs[r][c4 + 2] = v.z; Bs[r][c4 + 3] = v.w;
        }
        __syncthreads();
#pragma unroll
        for (int kk = 0; kk < 16; kk++) {
            float av[4], bv[4];
#pragma unroll
            for (int i = 0; i < 4; i++) av[i] = As[kk][ty * 4 + i];
#pragma unroll
            for (int j = 0; j < 4; j++) bv[j] = Bs[kk][tx * 4 + j];
#pragma unroll
            for (int i = 0; i < 4; i++)
#pragma unroll
                for (int j = 0; j < 4; j++) acc[i][j] += av[i] * bv[j];
        }
        __syncthreads();
    }
#pragma unroll
    for (int i = 0; i < 4; i++) {
        int gr = row0 + ty * 4 + i;
        if (gr >= NTOK) continue;
#pragma unroll
        for (int j = 0; j < 4; j++) {
            int gc = tx * 4 + j;
            long idx = ((long)(b * NTOK + gr)) * D + h * HD + gc;
            G[idx] = f2h(acc[i][j]);
        }
    }
}

// ================= setup pieces =================

__global__ __launch_bounds__(256) void patchify_kernel(const float* __restrict__ x, float* __restrict__ tok) {
    int idx = blockIdx.x * 256 + threadIdx.x;
    const int total = NB * NPATCH * D;
    if (idx >= total) return;
    int d = idx % D;
    int p = (idx / D) % NPATCH;
    int b = idx / (D * NPATCH);
    int c = d >> 8;
    int pi = (d >> 4) & 15;
    int pj = d & 15;
    int hp = p / 14, wp = p % 14;
    int row = hp * 16 + pi, col = wp * 16 + pj;
    tok[idx] = x[(((long)b * 3 + c) * 224 + row) * 224 + col];
}

__global__ __launch_bounds__(256) void cls_pos_kernel(float* __restrict__ h, const float* __restrict__ cls,
                                                      const float* __restrict__ pos) {
    int idx = blockIdx.x * 256 + threadIdx.x;
    const int total = NB * NTOK * D;
    if (idx >= total) return;
    int d = idx % D;
    int n = (idx / D) % NTOK;
    float v = pos[n * D + d];
    if (n == 0) h[idx] = cls[d] + v;
    else        h[idx] = h[idx] + v;
}

__global__ __launch_bounds__(256) void wcat_kernel(const float* __restrict__ w, float* __restrict__ Wm) {
    int idx = blockIdx.x * 256 + threadIdx.x;
    const int total = NH * D * HD;
    if (idx >= total) return;
    int k = idx & 63;
    int d = (idx >> 6) % D;
    int hh = idx / (D * HD);
    Wm[d * D + hh * HD + k] = w[idx];
}

// ---------------- f32 GEMM (patch embed only) ----------------
__global__ __launch_bounds__(256) void gemm_f32(
    const float* __restrict__ A, const float* __restrict__ B, float* __restrict__ C,
    const float* __restrict__ bias,
    int M, int N, int K, int lda, int ldb, int ldc,
    long sA1, long sC1) {
    int z = blockIdx.z;
    A += (long)z * sA1;
    long coff = (long)z * sC1;

    __shared__ float As[16][68];
    __shared__ float Bs[16][68];

    int t = threadIdx.x;
    int tx = t & 15, ty = t >> 4;
    int row0 = blockIdx.y * 64, col0 = blockIdx.x * 64;

    float acc[4][4] = {};

    for (int kt = 0; kt < K; kt += 16) {
        {
            int r = t >> 2;
            int c4 = (t & 3) << 2;
            int gr = row0 + r;
            int gk = kt + c4;
            float4 v = make_float4(0.f, 0.f, 0.f, 0.f);
            if (gr < M && gk + 3 < K) v = *(const float4*)(A + (long)gr * lda + gk);
            As[c4 + 0][r] = v.x; As[c4 + 1][r] = v.y; As[c4 + 2][r] = v.z; As[c4 + 3][r] = v.w;
        }
        {
            int r = t >> 4;
            int c4 = (t & 15) << 2;
            int gk = kt + r;
            int gc = col0 + c4;
            float4 v = make_float4(0.f, 0.f, 0.f, 0.f);
            if (gk < K && gc + 3 < N) v = *(const float4*)(B + (long)gk * ldb + gc);
            Bs[r][c4 + 0] = v.x; Bs[r][c4 + 1] = v.y; Bs[r][c4 + 2] = v.z; Bs[r][c4 + 3] = v.w;
        }
        __syncthreads();
#pragma unroll
        for (int kk = 0; kk < 16; kk++) {
            float av[4], bv[4];
#pragma unroll
            for (int i = 0; i < 4; i++) av[i] = As[kk][ty * 4 + i];
#pragma unroll
            for (int j = 0; j < 4; j++) bv[j] = Bs[kk][tx * 4 + j];
#pragma unroll
            for (int i = 0; i < 4; i++)
#pragma unroll
                for (int j = 0; j < 4; j++) acc[i][j] += av[i] * bv[j];
        }
        __syncthreads();
    }
#pragma unroll
    for (int i = 0; i < 4; i++) {
        int gr = row0 + ty * 4 + i;
        if (gr >= M) continue;
#pragma unroll
        for (int j = 0; j < 4; j++) {
            int gc = col0 + tx * 4 + j;
            if (gc >= N) continue;
            float v = acc[i][j];
            if (bias) v += bias[gc];
            C[coff + (long)gr * ldc + gc] = v;
        }
    }
}

// ---------------- COALESCED tiled transpose prep: dst[c][r] = f2h(src[r][c]) ----------------
// R, C multiples of 32. grid (C/32, R/32), block 256 (32x8).
__global__ __launch_bounds__(256) void prep_transpose_h(const float* __restrict__ src,
                                                        u16* __restrict__ dst, int R, int C) {
    __shared__ float tile[32][33];
    int c0 = blockIdx.x * 32, r0 = blockIdx.y * 32;
    int tx = threadIdx.x & 31, ty = threadIdx.x >> 5;
    for (int i = ty; i < 32; i += 8)
        tile[i][tx] = src[(long)(r0 + i) * C + c0 + tx];
    __syncthreads();
    for (int i = ty; i < 32; i += 8)
        dst[(long)(c0 + i) * R + r0 + tx] = f2h(tile[tx][i]);
}
__global__ __launch_bounds__(256) void prep_convert_h(const float* __restrict__ src,
                                                      u16* __restrict__ dst, int n) {
    int idx = blockIdx.x * 256 + threadIdx.x;
    if (idx >= n) return;
    dst[idx] = f2h(src[idx]);
}

extern "C" void kernel_launch(void* const* d_in, const int* in_sizes, int n_in,
                              void* d_out, int out_size, void* d_ws, size_t ws_size,
                              hipStream_t stream) {
    const float* x        = (const float*)d_in[0];
    const float* patch_w  = (const float*)d_in[1];
    const float* patch_b  = (const float*)d_in[2];
    const float* cls_tok  = (const float*)d_in[3];
    const float* pos_emb  = (const float*)d_in[4];
    const float* ln_gamma = (const float*)d_in[5];
    const float* ln_beta  = (const float*)d_in[6];
    const float* wq       = (const float*)d_in[7];
    const float* wk       = (const float*)d_in[8];
    const float* xi       = (const float*)d_in[9];
    const float* out_gamma= (const float*)d_in[10];
    const float* out_beta = (const float*)d_in[11];
    const float* out_w    = (const float*)d_in[12];
    const float* out_b    = (const float*)d_in[13];
    float* out = (float*)d_out;

    float* ws = (float*)d_ws;
    const long SZ = SZL;
    const long AR = (long)AROWS * D;
    float* h  = ws;
    float* Qb = ws + SZ;
    float* Kb = ws + 2 * SZ;
    u16* gh16    = (u16*)(ws + 3 * SZ);
    u16* WmQTh16 = gh16 + AR;
    u16* WmKTh16 = WmQTh16 + DD;
    u16* WmQh16  = WmKTh16 + DD;
    u16* WmKh16  = WmQh16 + DD;
    u16* xiTh16  = WmKh16 + DD;
    u16* xibh16  = xiTh16 + DH;
    u16* G1h16   = xibh16 + DH;
    u16* G2h16   = G1h16 + AR;
    u16* HH16    = G2h16 + AR;
    u16* owTh16  = HH16 + (long)AROWS * HOP;
    // shared region (sequenced aliasing): part (6*SZ u16) | Pt (192*PBH u16) | tok/WmQ/WmK (setup f32)
    char* R1c = (char*)(owTh16 + DD);
    u16* Pt16   = (u16*)R1c;
    u16* part16 = (u16*)R1c;
    float* tok  = (float*)R1c;
    float* WmQ  = (float*)R1c + SZ;
    float* WmK  = WmQ + DD;

    // ---- setup ----
    patchify_kernel<<<(NB * NPATCH * D + 255) / 256, 256, 0, stream>>>(x, tok);
    wcat_kernel<<<(NH * D * HD + 255) / 256, 256, 0, stream>>>(wq, WmQ);
    wcat_kernel<<<(NH * D * HD + 255) / 256, 256, 0, stream>>>(wk, WmK);
    prep_transpose_h<<<dim3(24, 24), 256, 0, stream>>>(WmQ, WmQTh16, 768, 768);
    prep_transpose_h<<<dim3(24, 24), 256, 0, stream>>>(WmK, WmKTh16, 768, 768);
    prep_convert_h<<<(DD + 255) / 256, 256, 0, stream>>>(WmQ, WmQh16, DD);
    prep_convert_h<<<(DD + 255) / 256, 256, 0, stream>>>(WmK, WmKh16, DD);
    prep_transpose_h<<<dim3(96, 24), 256, 0, stream>>>(xi, xiTh16, 768, HOP);
    prep_convert_h<<<(DH + 255) / 256, 256, 0, stream>>>(xi, xibh16, DH);
    prep_transpose_h<<<dim3(24, 24), 256, 0, stream>>>(out_w, owTh16, 768, 768);
    // patch embed: f32 (h0 seed stays f32 — sensitivity firewall)
    gemm_f32<<<dim3(12, 4, NB), 256, 0, stream>>>(
        tok, patch_w, h + D, patch_b, NPATCH, D, D, D, D, D,
        (long)NPATCH * D, (long)NTOK * D);
    cls_pos_kernel<<<(NB * NTOK * D + 255) / 256, 256, 0, stream>>>(h, cls_tok, pos_emb);

    for (int step = 0; step < TSTEPS; step++) {
        ln_fuse_kernel<<<NROWS, 256, 0, stream>>>(h, gh16, part16, ln_gamma, ln_beta,
                                                  0, step > 0 ? 1 : 0, 1);
        fused_proj<<<dim3(36, 25), 256, 0, stream>>>(gh16, WmQTh16, WmKTh16, xiTh16, Qb, Kb, HH16);
        attn_p_kernel<<<192, 256, 0, stream>>>(Qb, Kb, Pt16);
        attn_g_kernel<<<dim3(1, 4, 384), 256, 0, stream>>>(Pt16, Qb, Kb, G1h16, G2h16);
        gemm_h16_fused<<<dim3(6, 25, 6), 256, 0, stream>>>(
            G1h16, G2h16, HH16, WmQh16, WmKh16, xibh16, part16);
    }

    // ---- final: reduce + LN (compact) -> fp16, then out projection (fp16 MFMA) ----
    ln_fuse_kernel<<<NPROWS, 256, 0, stream>>>(h, gh16, part16, out_gamma, out_beta, 1, 1, 0);
    gemm_h16<<<dim3(6, 25, 1), 256, 0, stream>>>(
        gh16, owTh16, out, out_b, NPROWS, D, D, D, D, D, 0, 0, 0, 0);
}

// Round 16
// 1352.180 us; speedup vs baseline: 1.3662x; 1.3662x over previous
//
#include <hip/hip_runtime.h>

#define NB 16
#define NTOK 197
#define NPATCH 196
#define D 768
#define NH 12
#define HD 64
#define HOP 3072
#define TSTEPS 6
#define BETA_F 0.125f
#define PLD 208                 // Pt leading dim (fp16)
#define PBH (NTOK * PLD)        // 40976
#define NROWS (NB * NTOK)       // 3152
#define NPROWS (NB * NPATCH)    // 3136
#define AROWS 3200              // padded rows for MFMA A-side staging
#define DD (768 * 768)
#define DH (768 * 3072)
#define SZL ((long)NROWS * D)   // 2,420,736

typedef unsigned short u16;
typedef __attribute__((ext_vector_type(8))) _Float16 f16x8;
typedef __attribute__((ext_vector_type(4))) float f32x4;

#define FLAG_ACC 1
#define FLAG_RELU 2
#define FLAG_H16 4

__device__ __forceinline__ u16 f2h(float f) {
    union { _Float16 h; u16 u; } cv;
    cv.h = (_Float16)f;
    return cv.u;
}
__device__ __forceinline__ float h2f(u16 v) {
    union { _Float16 h; u16 u; } cv;
    cv.u = v;
    return (float)cv.h;
}

__device__ __forceinline__ void gld16(const void* g, void* l) {
    __builtin_amdgcn_global_load_lds((const __attribute__((address_space(1))) void*)g,
                                     (__attribute__((address_space(3))) void*)l, 16, 0, 0);
}

// ---------------- single-fp16 MFMA GEMM (out-projection) ----------------
__global__ __launch_bounds__(256) void gemm_h16(
    const u16* __restrict__ A, const u16* __restrict__ B,
    void* __restrict__ Cv, const float* __restrict__ bias,
    int M, int N, int K, int lda, int ldbt, int ldc, int flags,
    long sAz, long sBz, long sCz) {
    __shared__ __align__(16) u16 As[128 * 32];
    __shared__ __align__(16) u16 Bs[128 * 32];
    int zz = blockIdx.z;
    A += (long)zz * sAz;
    B += (long)zz * sBz;
    long czoff = (long)zz * sCz;
    int t = threadIdx.x;
    int w = t >> 6, lane = t & 63;
    int lr = lane & 15, lg = lane >> 4;
    int wr = w >> 1, wc = w & 1;
    long row0 = (long)blockIdx.y * 128, col0 = (long)blockIdx.x * 128;

    f32x4 acc[4][4];
#pragma unroll
    for (int i = 0; i < 4; i++)
#pragma unroll
        for (int j = 0; j < 4; j++) acc[i][j] = (f32x4){0.f, 0.f, 0.f, 0.f};

    int c0 = w * 64 + lane;
    int r0s = c0 >> 2, k0s = (((c0 & 3) ^ ((r0s >> 1) & 3)) << 3);
    int c1 = 256 + w * 64 + lane;
    int r1s = c1 >> 2, k1s = (((c1 & 3) ^ ((r1s >> 1) & 3)) << 3);

    for (int kt = 0; kt < K; kt += 32) {
        const u16* AB = A + row0 * lda + kt;
        const u16* BB = B + col0 * ldbt + kt;
        gld16(AB + (long)r0s * lda + k0s, (char*)As + (w * 64) * 16);
        gld16(AB + (long)r1s * lda + k1s, (char*)As + (256 + w * 64) * 16);
        gld16(BB + (long)r0s * ldbt + k0s, (char*)Bs + (w * 64) * 16);
        gld16(BB + (long)r1s * ldbt + k1s, (char*)Bs + (256 + w * 64) * 16);
        __syncthreads();
        f16x8 af[4], bf[4];
#pragma unroll
        for (int mi = 0; mi < 4; mi++) {
            int row = wr * 64 + mi * 16 + lr;
            af[mi] = *(const f16x8*)&As[row * 32 + ((lg ^ ((row >> 1) & 3)) << 3)];
        }
#pragma unroll
        for (int ni = 0; ni < 4; ni++) {
            int row = wc * 64 + ni * 16 + lr;
            bf[ni] = *(const f16x8*)&Bs[row * 32 + ((lg ^ ((row >> 1) & 3)) << 3)];
        }
#pragma unroll
        for (int mi = 0; mi < 4; mi++)
#pragma unroll
            for (int ni = 0; ni < 4; ni++)
                acc[mi][ni] = __builtin_amdgcn_mfma_f32_16x16x32_f16(af[mi], bf[ni], acc[mi][ni], 0, 0, 0);
        __syncthreads();
    }

    long mbase = row0 + wr * 64;
    long nbase = col0 + wc * 64;
#pragma unroll
    for (int mi = 0; mi < 4; mi++) {
#pragma unroll
        for (int r = 0; r < 4; r++) {
            long grow = mbase + mi * 16 + lg * 4 + r;
            if (grow >= M) continue;
#pragma unroll
            for (int ni = 0; ni < 4; ni++) {
                long gcol = nbase + ni * 16 + lr;
                float v = acc[mi][ni][r];
                if (bias) v += bias[gcol];
                if (flags & FLAG_RELU) v = fmaxf(v, 0.f);
                long idx = czoff + grow * ldc + gcol;
                if (flags & FLAG_ACC) ((float*)Cv)[idx] += v;
                else if (flags & FLAG_H16) ((u16*)Cv)[idx] = f2h(v);
                else ((float*)Cv)[idx] = v;
            }
        }
    }
}

// ---------------- fused projection: QK (f32 out) + Hopfield-1 (fp16+relu) ----------------
__global__ __launch_bounds__(256) void fused_proj(
    const u16* __restrict__ A,
    const u16* __restrict__ WQT, const u16* __restrict__ WKT, const u16* __restrict__ XIT,
    float* __restrict__ Qb, float* __restrict__ Kb, u16* __restrict__ HH) {
    __shared__ __align__(16) u16 As[128 * 32];
    __shared__ __align__(16) u16 Bs[128 * 32];
    int cx = blockIdx.x;
    const u16* B; int ldc; long col0; int mode;
    if (cx < 6)       { B = WQT; ldc = 768;  col0 = (long)cx * 128;        mode = 0; }
    else if (cx < 12) { B = WKT; ldc = 768;  col0 = (long)(cx - 6) * 128;  mode = 1; }
    else              { B = XIT; ldc = 3072; col0 = (long)(cx - 12) * 128; mode = 2; }
    int t = threadIdx.x;
    int w = t >> 6, lane = t & 63;
    int lr = lane & 15, lg = lane >> 4;
    int wr = w >> 1, wc = w & 1;
    long row0 = (long)blockIdx.y * 128;

    f32x4 acc[4][4];
#pragma unroll
    for (int i = 0; i < 4; i++)
#pragma unroll
        for (int j = 0; j < 4; j++) acc[i][j] = (f32x4){0.f, 0.f, 0.f, 0.f};

    int c0 = w * 64 + lane;
    int r0s = c0 >> 2, k0s = (((c0 & 3) ^ ((r0s >> 1) & 3)) << 3);
    int c1 = 256 + w * 64 + lane;
    int r1s = c1 >> 2, k1s = (((c1 & 3) ^ ((r1s >> 1) & 3)) << 3);

    for (int kt = 0; kt < 768; kt += 32) {
        const u16* AB = A + row0 * 768 + kt;
        const u16* BB = B + col0 * 768 + kt;
        gld16(AB + (long)r0s * 768 + k0s, (char*)As + (w * 64) * 16);
        gld16(AB + (long)r1s * 768 + k1s, (char*)As + (256 + w * 64) * 16);
        gld16(BB + (long)r0s * 768 + k0s, (char*)Bs + (w * 64) * 16);
        gld16(BB + (long)r1s * 768 + k1s, (char*)Bs + (256 + w * 64) * 16);
        __syncthreads();
        f16x8 af[4], bf[4];
#pragma unroll
        for (int mi = 0; mi < 4; mi++) {
            int row = wr * 64 + mi * 16 + lr;
            af[mi] = *(const f16x8*)&As[row * 32 + ((lg ^ ((row >> 1) & 3)) << 3)];
        }
#pragma unroll
        for (int ni = 0; ni < 4; ni++) {
            int row = wc * 64 + ni * 16 + lr;
            bf[ni] = *(const f16x8*)&Bs[row * 32 + ((lg ^ ((row >> 1) & 3)) << 3)];
        }
#pragma unroll
        for (int mi = 0; mi < 4; mi++)
#pragma unroll
            for (int ni = 0; ni < 4; ni++)
                acc[mi][ni] = __builtin_amdgcn_mfma_f32_16x16x32_f16(af[mi], bf[ni], acc[mi][ni], 0, 0, 0);
        __syncthreads();
    }

    long mbase = row0 + wr * 64;
    long nbase = col0 + wc * 64;
#pragma unroll
    for (int mi = 0; mi < 4; mi++) {
#pragma unroll
        for (int r = 0; r < 4; r++) {
            long grow = mbase + mi * 16 + lg * 4 + r;
            if (grow >= NROWS) continue;
#pragma unroll
            for (int ni = 0; ni < 4; ni++) {
                long gcol = nbase + ni * 16 + lr;
                float v = acc[mi][ni][r];
                long idx = grow * ldc + gcol;
                if (mode == 0)      Qb[idx] = v;
                else if (mode == 1) Kb[idx] = v;
                else                HH[idx] = f2h(fmaxf(v, 0.f));
            }
        }
    }
}

// ---------------- fused accumulate GEMM: 6 split-K partials -> fp16 slabs ----------------
__global__ __launch_bounds__(256) void gemm_h16_fused(
    const u16* __restrict__ G1, const u16* __restrict__ G2, const u16* __restrict__ HH,
    const u16* __restrict__ WQ, const u16* __restrict__ WK, const u16* __restrict__ XB,
    u16* __restrict__ part) {
    __shared__ __align__(16) u16 As[128 * 32];
    __shared__ __align__(16) u16 Bs[128 * 32];
    int zz = blockIdx.z;
    const u16* A; const u16* B; int lda; int K0;
    if (zz == 0)      { A = G1; B = WQ; lda = 768;  K0 = 0; }
    else if (zz == 1) { A = G2; B = WK; lda = 768;  K0 = 0; }
    else              { A = HH; B = XB; lda = 3072; K0 = (zz - 2) * 768; }
    u16* C = part + (long)zz * SZL;

    int t = threadIdx.x;
    int w = t >> 6, lane = t & 63;
    int lr = lane & 15, lg = lane >> 4;
    int wr = w >> 1, wc = w & 1;
    long row0 = (long)blockIdx.y * 128, col0 = (long)blockIdx.x * 128;

    f32x4 acc[4][4];
#pragma unroll
    for (int i = 0; i < 4; i++)
#pragma unroll
        for (int j = 0; j < 4; j++) acc[i][j] = (f32x4){0.f, 0.f, 0.f, 0.f};

    int c0 = w * 64 + lane;
    int r0s = c0 >> 2, k0s = (((c0 & 3) ^ ((r0s >> 1) & 3)) << 3);
    int c1 = 256 + w * 64 + lane;
    int r1s = c1 >> 2, k1s = (((c1 & 3) ^ ((r1s >> 1) & 3)) << 3);

    for (int kt = K0; kt < K0 + 768; kt += 32) {
        const u16* AB = A + row0 * lda + kt;
        const u16* BB = B + col0 * (long)lda + kt;
        gld16(AB + (long)r0s * lda + k0s, (char*)As + (w * 64) * 16);
        gld16(AB + (long)r1s * lda + k1s, (char*)As + (256 + w * 64) * 16);
        gld16(BB + (long)r0s * lda + k0s, (char*)Bs + (w * 64) * 16);
        gld16(BB + (long)r1s * lda + k1s, (char*)Bs + (256 + w * 64) * 16);
        __syncthreads();
        f16x8 af[4], bf[4];
#pragma unroll
        for (int mi = 0; mi < 4; mi++) {
            int row = wr * 64 + mi * 16 + lr;
            af[mi] = *(const f16x8*)&As[row * 32 + ((lg ^ ((row >> 1) & 3)) << 3)];
        }
#pragma unroll
        for (int ni = 0; ni < 4; ni++) {
            int row = wc * 64 + ni * 16 + lr;
            bf[ni] = *(const f16x8*)&Bs[row * 32 + ((lg ^ ((row >> 1) & 3)) << 3)];
        }
#pragma unroll
        for (int mi = 0; mi < 4; mi++)
#pragma unroll
            for (int ni = 0; ni < 4; ni++)
                acc[mi][ni] = __builtin_amdgcn_mfma_f32_16x16x32_f16(af[mi], bf[ni], acc[mi][ni], 0, 0, 0);
        __syncthreads();
    }

    long mbase = row0 + wr * 64;
    long nbase = col0 + wc * 64;
#pragma unroll
    for (int mi = 0; mi < 4; mi++) {
#pragma unroll
        for (int r = 0; r < 4; r++) {
            long grow = mbase + mi * 16 + lg * 4 + r;
            if (grow >= NROWS) continue;
#pragma unroll
            for (int ni = 0; ni < 4; ni++) {
                long gcol = nbase + ni * 16 + lr;
                C[grow * D + gcol] = f2h(acc[mi][ni][r]);
            }
        }
    }
}

// ---------------- fused reduce + layernorm: h (+= 6 fp16 slabs) -> LN -> fp16 ----------------
__global__ __launch_bounds__(256) void ln_fuse_kernel(
    float* __restrict__ X, u16* __restrict__ Yh16, const u16* __restrict__ part,
    const float* __restrict__ gamma, const float* __restrict__ beta,
    int compact, int doReduce, int writeBack) {
    int r = blockIdx.x;
    long xrow = compact ? ((long)(r / NPATCH) * NTOK + 1 + (r % NPATCH)) : (long)r;
    float* x = X + xrow * D;
    int t = threadIdx.x;
    float v[3];
    float s = 0.f, ss = 0.f;
#pragma unroll
    for (int i = 0; i < 3; i++) {
        int c = t + 256 * i;
        float val = x[c];
        if (doReduce) {
            long off = xrow * D + c;
            float p01 = h2f(part[off]) + h2f(part[SZL + off]);
            float p23 = h2f(part[2 * SZL + off]) + h2f(part[3 * SZL + off]);
            float p45 = h2f(part[4 * SZL + off]) + h2f(part[5 * SZL + off]);
            val += (p01 + p23) + p45;
            if (writeBack) x[c] = val;
        }
        v[i] = val;
        s += val;
        ss += val * val;
    }
    __shared__ float red[8];
    for (int off = 32; off; off >>= 1) {
        s += __shfl_down(s, off, 64);
        ss += __shfl_down(ss, off, 64);
    }
    int wid = t >> 6, lane = t & 63;
    if (lane == 0) { red[wid] = s; red[4 + wid] = ss; }
    __syncthreads();
    s = red[0] + red[1] + red[2] + red[3];
    ss = red[4] + red[5] + red[6] + red[7];
    float mu = s * (1.f / 768.f);
    float var = ss * (1.f / 768.f) - mu * mu;
    float inv = rsqrtf(var + 1e-5f);
#pragma unroll
    for (int i = 0; i < 3; i++) {
        int c = t + 256 * i;
        float yv = gamma[c] * (v[i] - mu) * inv + beta[c];
        Yh16[(long)r * D + c] = f2h(yv);
    }
}

// ---------------- parallel f32 attention softmax -> fp16 Pt (R14 version: grid 192x13) ----------------
__global__ __launch_bounds__(256) void attn_p_kernel(const float* __restrict__ Q, const float* __restrict__ K,
                                                     u16* __restrict__ Pt) {
    __shared__ float Ks[NTOK][65];
    int bh = blockIdx.x, mt = blockIdx.y;
    int b = bh / NH, h = bh % NH;
    int t = threadIdx.x;
    const float* Kb = K + (long)b * NTOK * D + h * HD;
    for (int i = t; i < NTOK * 16; i += 256) {
        int n = i >> 4, k4 = (i & 15) << 2;
        float4 v = *(const float4*)(Kb + (long)n * D + k4);
        Ks[n][k4] = v.x; Ks[n][k4 + 1] = v.y; Ks[n][k4 + 2] = v.z; Ks[n][k4 + 3] = v.w;
    }
    __syncthreads();
    int ql = t >> 4, l16 = t & 15;
    int m = mt * 16 + ql;
    int mr = m < NTOK ? m : NTOK - 1;
    const float* Qrow = Q + (long)(b * NTOK + mr) * D + h * HD;
    float q[64];
#pragma unroll
    for (int k = 0; k < 64; k += 4) {
        float4 v = *(const float4*)(Qrow + k);
        q[k] = v.x; q[k + 1] = v.y; q[k + 2] = v.z; q[k + 3] = v.w;
    }
    float s[13];
    float mx = -1e30f;
#pragma unroll
    for (int i = 0; i < 13; i++) {
        int n = i * 16 + l16;
        const float* kr = Ks[n < NTOK ? n : 0];
        float a0 = 0.f, a1 = 0.f, a2 = 0.f, a3 = 0.f;
#pragma unroll
        for (int k = 0; k < 64; k += 4) {
            a0 += kr[k] * q[k];
            a1 += kr[k + 1] * q[k + 1];
            a2 += kr[k + 2] * q[k + 2];
            a3 += kr[k + 3] * q[k + 3];
        }
        float sv = ((a0 + a1) + (a2 + a3)) * BETA_F;
        s[i] = (n < NTOK) ? sv : -1e30f;
        mx = fmaxf(mx, s[i]);
    }
    mx = fmaxf(mx, __shfl_xor(mx, 1, 64));
    mx = fmaxf(mx, __shfl_xor(mx, 2, 64));
    mx = fmaxf(mx, __shfl_xor(mx, 4, 64));
    mx = fmaxf(mx, __shfl_xor(mx, 8, 64));
    float ssum = 0.f;
#pragma unroll
    for (int i = 0; i < 13; i++) {
        float e = (s[i] > -1e29f) ? __expf(s[i] - mx) : 0.f;
        s[i] = e;
        ssum += e;
    }
    ssum += __shfl_xor(ssum, 1, 64);
    ssum += __shfl_xor(ssum, 2, 64);
    ssum += __shfl_xor(ssum, 4, 64);
    ssum += __shfl_xor(ssum, 8, 64);
    float inv = 1.f / ssum;
    if (m < NTOK) {
        u16* PtB = Pt + (long)bh * PBH;
#pragma unroll
        for (int i = 0; i < 13; i++) {
            int n = i * 16 + l16;
            PtB[(long)m * PLD + n] = (n < NTOK) ? f2h(s[i] * inv) : (u16)0;
        }
    }
}

// ---------------- attention grads: G1 (A normal) + G2 (A transposed), fp16 Pt in ----------------
__global__ __launch_bounds__(256) void attn_g_kernel(
    const u16* __restrict__ Pt, const float* __restrict__ Qb, const float* __restrict__ Kb,
    u16* __restrict__ G1, u16* __restrict__ G2) {
    __shared__ float As[16][68];
    __shared__ float Bs[16][68];
    int z = blockIdx.z;
    int which = z / 192, bh = z - which * 192;
    int b = bh / NH, h = bh % NH;
    const u16* A = Pt + (long)bh * PBH;
    const float* B = (which ? Qb : Kb) + (long)b * NTOK * D + h * HD;
    u16* G = which ? G2 : G1;

    int t = threadIdx.x;
    int tx = t & 15, ty = t >> 4;
    int row0 = blockIdx.y * 64;

    float acc[4][4] = {};

    for (int kt = 0; kt < NTOK; kt += 16) {
        if (which == 0) {
            int r = t >> 2, c4 = (t & 3) << 2;
            int gr = row0 + r, gk = kt + c4;
            float4 v = make_float4(0.f, 0.f, 0.f, 0.f);
            if (gr < NTOK) {
                ushort4 u = *(const ushort4*)(A + (long)gr * PLD + gk);
                v = make_float4(h2f(u.x), h2f(u.y), h2f(u.z), h2f(u.w));
            }
            As[c4 + 0][r] = v.x; As[c4 + 1][r] = v.y; As[c4 + 2][r] = v.z; As[c4 + 3][r] = v.w;
        } else {
            int rr = t >> 4, c4 = (t & 15) << 2;
            int gk = kt + rr, gc = row0 + c4;
            float4 v = make_float4(0.f, 0.f, 0.f, 0.f);
            if (gk < NTOK && gc + 3 < PLD) {
                ushort4 u = *(const ushort4*)(A + (long)gk * PLD + gc);
                v = make_float4(h2f(u.x), h2f(u.y), h2f(u.z), h2f(u.w));
            }
            As[rr][c4 + 0] = v.x; As[rr][c4 + 1] = v.y; As[rr][c4 + 2] = v.z; As[rr][c4 + 3] = v.w;
        }
        {
            int r = t >> 4, c4 = (t & 15) << 2;
            int gk = kt + r;
            float4 v = make_float4(0.f, 0.f, 0.f, 0.f);
            if (gk < NTOK) v = *(const float4*)(B + (long)gk * D + c4);
            Bs[r][c4 + 0] = v.x; Bs[r][c4 + 1] = v.y; Bs[r][c4 + 2] = v.z; Bs[r][c4 + 3] = v.w;
        }
        __syncthreads();
#pragma unroll
        for (int kk = 0; kk < 16; kk++) {
            float av[4], bv[4];
#pragma unroll
            for (int i = 0; i < 4; i++) av[i] = As[kk][ty * 4 + i];
#pragma unroll
            for (int j = 0; j < 4; j++) bv[j] = Bs[kk][tx * 4 + j];
#pragma unroll
            for (int i = 0; i < 4; i++)
#pragma unroll
                for (int j = 0; j < 4; j++) acc[i][j] += av[i] * bv[j];
        }
        __syncthreads();
    }
#pragma unroll
    for (int i = 0; i < 4; i++) {
        int gr = row0 + ty * 4 + i;
        if (gr >= NTOK) continue;
#pragma unroll
        for (int j = 0; j < 4; j++) {
            int gc = tx * 4 + j;
            long idx = ((long)(b * NTOK + gr)) * D + h * HD + gc;
            G[idx] = f2h(acc[i][j]);
        }
    }
}

// ================= setup pieces =================

__global__ __launch_bounds__(256) void patchify_kernel(const float* __restrict__ x, float* __restrict__ tok) {
    int idx = blockIdx.x * 256 + threadIdx.x;
    const int total = NB * NPATCH * D;
    if (idx >= total) return;
    int d = idx % D;
    int p = (idx / D) % NPATCH;
    int b = idx / (D * NPATCH);
    int c = d >> 8;
    int pi = (d >> 4) & 15;
    int pj = d & 15;
    int hp = p / 14, wp = p % 14;
    int row = hp * 16 + pi, col = wp * 16 + pj;
    tok[idx] = x[(((long)b * 3 + c) * 224 + row) * 224 + col];
}

__global__ __launch_bounds__(256) void cls_pos_kernel(float* __restrict__ h, const float* __restrict__ cls,
                                                      const float* __restrict__ pos) {
    int idx = blockIdx.x * 256 + threadIdx.x;
    const int total = NB * NTOK * D;
    if (idx >= total) return;
    int d = idx % D;
    int n = (idx / D) % NTOK;
    float v = pos[n * D + d];
    if (n == 0) h[idx] = cls[d] + v;
    else        h[idx] = h[idx] + v;
}

__global__ __launch_bounds__(256) void wcat_kernel(const float* __restrict__ w, float* __restrict__ Wm) {
    int idx = blockIdx.x * 256 + threadIdx.x;
    const int total = NH * D * HD;
    if (idx >= total) return;
    int k = idx & 63;
    int d = (idx >> 6) % D;
    int hh = idx / (D * HD);
    Wm[d * D + hh * HD + k] = w[idx];
}

// ---------------- f32 GEMM (patch embed only) ----------------
__global__ __launch_bounds__(256) void gemm_f32(
    const float* __restrict__ A, const float* __restrict__ B, float* __restrict__ C,
    const float* __restrict__ bias,
    int M, int N, int K, int lda, int ldb, int ldc,
    long sA1, long sC1) {
    int z = blockIdx.z;
    A += (long)z * sA1;
    long coff = (long)z * sC1;

    __shared__ float As[16][68];
    __shared__ float Bs[16][68];

    int t = threadIdx.x;
    int tx = t & 15, ty = t >> 4;
    int row0 = blockIdx.y * 64, col0 = blockIdx.x * 64;

    float acc[4][4] = {};

    for (int kt = 0; kt < K; kt += 16) {
        {
            int r = t >> 2;
            int c4 = (t & 3) << 2;
            int gr = row0 + r;
            int gk = kt + c4;
            float4 v = make_float4(0.f, 0.f, 0.f, 0.f);
            if (gr < M && gk + 3 < K) v = *(const float4*)(A + (long)gr * lda + gk);
            As[c4 + 0][r] = v.x; As[c4 + 1][r] = v.y; As[c4 + 2][r] = v.z; As[c4 + 3][r] = v.w;
        }
        {
            int r = t >> 4;
            int c4 = (t & 15) << 2;
            int gk = kt + r;
            int gc = col0 + c4;
            float4 v = make_float4(0.f, 0.f, 0.f, 0.f);
            if (gk < K && gc + 3 < N) v = *(const float4*)(B + (long)gk * ldb + gc);
            Bs[r][c4 + 0] = v.x; Bs[r][c4 + 1] = v.y; Bs[r][c4 + 2] = v.z; Bs[r][c4 + 3] = v.w;
        }
        __syncthreads();
#pragma unroll
        for (int kk = 0; kk < 16; kk++) {
            float av[4], bv[4];
#pragma unroll
            for (int i = 0; i < 4; i++) av[i] = As[kk][ty * 4 + i];
#pragma unroll
            for (int j = 0; j < 4; j++) bv[j] = Bs[kk][tx * 4 + j];
#pragma unroll
            for (int i = 0; i < 4; i++)
#pragma unroll
                for (int j = 0; j < 4; j++) acc[i][j] += av[i] * bv[j];
        }
        __syncthreads();
    }
#pragma unroll
    for (int i = 0; i < 4; i++) {
        int gr = row0 + ty * 4 + i;
        if (gr >= M) continue;
#pragma unroll
        for (int j = 0; j < 4; j++) {
            int gc = col0 + tx * 4 + j;
            if (gc >= N) continue;
            float v = acc[i][j];
            if (bias) v += bias[gc];
            C[coff + (long)gr * ldc + gc] = v;
        }
    }
}

// ---------------- COALESCED tiled transpose prep: dst[c][r] = f2h(src[r][c]) ----------------
__global__ __launch_bounds__(256) void prep_transpose_h(const float* __restrict__ src,
                                                        u16* __restrict__ dst, int R, int C) {
    __shared__ float tile[32][33];
    int c0 = blockIdx.x * 32, r0 = blockIdx.y * 32;
    int tx = threadIdx.x & 31, ty = threadIdx.x >> 5;
    for (int i = ty; i < 32; i += 8)
        tile[i][tx] = src[(long)(r0 + i) * C + c0 + tx];
    __syncthreads();
    for (int i = ty; i < 32; i += 8)
        dst[(long)(c0 + i) * R + r0 + tx] = f2h(tile[tx][i]);
}
__global__ __launch_bounds__(256) void prep_convert_h(const float* __restrict__ src,
                                                      u16* __restrict__ dst, int n) {
    int idx = blockIdx.x * 256 + threadIdx.x;
    if (idx >= n) return;
    dst[idx] = f2h(src[idx]);
}

extern "C" void kernel_launch(void* const* d_in, const int* in_sizes, int n_in,
                              void* d_out, int out_size, void* d_ws, size_t ws_size,
                              hipStream_t stream) {
    const float* x        = (const float*)d_in[0];
    const float* patch_w  = (const float*)d_in[1];
    const float* patch_b  = (const float*)d_in[2];
    const float* cls_tok  = (const float*)d_in[3];
    const float* pos_emb  = (const float*)d_in[4];
    const float* ln_gamma = (const float*)d_in[5];
    const float* ln_beta  = (const float*)d_in[6];
    const float* wq       = (const float*)d_in[7];
    const float* wk       = (const float*)d_in[8];
    const float* xi       = (const float*)d_in[9];
    const float* out_gamma= (const float*)d_in[10];
    const float* out_beta = (const float*)d_in[11];
    const float* out_w    = (const float*)d_in[12];
    const float* out_b    = (const float*)d_in[13];
    float* out = (float*)d_out;

    float* ws = (float*)d_ws;
    const long SZ = SZL;
    const long AR = (long)AROWS * D;
    float* h  = ws;
    float* Qb = ws + SZ;
    float* Kb = ws + 2 * SZ;
    u16* gh16    = (u16*)(ws + 3 * SZ);
    u16* WmQTh16 = gh16 + AR;
    u16* WmKTh16 = WmQTh16 + DD;
    u16* WmQh16  = WmKTh16 + DD;
    u16* WmKh16  = WmQh16 + DD;
    u16* xiTh16  = WmKh16 + DD;
    u16* xibh16  = xiTh16 + DH;
    u16* G1h16   = xibh16 + DH;
    u16* G2h16   = G1h16 + AR;
    u16* HH16    = G2h16 + AR;
    u16* owTh16  = HH16 + (long)AROWS * HOP;
    // shared region (sequenced aliasing): part (6*SZ u16) | Pt (192*PBH u16) | tok/WmQ/WmK (setup f32)
    char* R1c = (char*)(owTh16 + DD);
    u16* Pt16   = (u16*)R1c;
    u16* part16 = (u16*)R1c;
    float* tok  = (float*)R1c;
    float* WmQ  = (float*)R1c + SZ;
    float* WmK  = WmQ + DD;

    // ---- setup ----
    patchify_kernel<<<(NB * NPATCH * D + 255) / 256, 256, 0, stream>>>(x, tok);
    wcat_kernel<<<(NH * D * HD + 255) / 256, 256, 0, stream>>>(wq, WmQ);
    wcat_kernel<<<(NH * D * HD + 255) / 256, 256, 0, stream>>>(wk, WmK);
    prep_transpose_h<<<dim3(24, 24), 256, 0, stream>>>(WmQ, WmQTh16, 768, 768);
    prep_transpose_h<<<dim3(24, 24), 256, 0, stream>>>(WmK, WmKTh16, 768, 768);
    prep_convert_h<<<(DD + 255) / 256, 256, 0, stream>>>(WmQ, WmQh16, DD);
    prep_convert_h<<<(DD + 255) / 256, 256, 0, stream>>>(WmK, WmKh16, DD);
    prep_transpose_h<<<dim3(96, 24), 256, 0, stream>>>(xi, xiTh16, 768, HOP);
    prep_convert_h<<<(DH + 255) / 256, 256, 0, stream>>>(xi, xibh16, DH);
    prep_transpose_h<<<dim3(24, 24), 256, 0, stream>>>(out_w, owTh16, 768, 768);
    // patch embed: f32 (h0 seed stays f32 — sensitivity firewall)
    gemm_f32<<<dim3(12, 4, NB), 256, 0, stream>>>(
        tok, patch_w, h + D, patch_b, NPATCH, D, D, D, D, D,
        (long)NPATCH * D, (long)NTOK * D);
    cls_pos_kernel<<<(NB * NTOK * D + 255) / 256, 256, 0, stream>>>(h, cls_tok, pos_emb);

    for (int step = 0; step < TSTEPS; step++) {
        ln_fuse_kernel<<<NROWS, 256, 0, stream>>>(h, gh16, part16, ln_gamma, ln_beta,
                                                  0, step > 0 ? 1 : 0, 1);
        fused_proj<<<dim3(36, 25), 256, 0, stream>>>(gh16, WmQTh16, WmKTh16, xiTh16, Qb, Kb, HH16);
        attn_p_kernel<<<dim3(192, 13), 256, 0, stream>>>(Qb, Kb, Pt16);
        attn_g_kernel<<<dim3(1, 4, 384), 256, 0, stream>>>(Pt16, Qb, Kb, G1h16, G2h16);
        gemm_h16_fused<<<dim3(6, 25, 6), 256, 0, stream>>>(
            G1h16, G2h16, HH16, WmQh16, WmKh16, xibh16, part16);
    }

    // ---- final: reduce + LN (compact) -> fp16, then out projection (fp16 MFMA) ----
    ln_fuse_kernel<<<NPROWS, 256, 0, stream>>>(h, gh16, part16, out_gamma, out_beta, 1, 1, 0);
    gemm_h16<<<dim3(6, 25, 1), 256, 0, stream>>>(
        gh16, owTh16, out, out_b, NPROWS, D, D, D, D, D, 0, 0, 0, 0);
}

// Round 17
// 1162.833 us; speedup vs baseline: 1.5886x; 1.1628x over previous
//
#include <hip/hip_runtime.h>

#define NB 16
#define NTOK 197
#define NPATCH 196
#define D 768
#define NH 12
#define HD 64
#define HOP 3072
#define TSTEPS 6
#define BETA_F 0.125f
#define PLD 208                 // Pt leading dim (fp16)
#define PBH (NTOK * PLD)        // 40976
#define NROWS (NB * NTOK)       // 3152
#define NPROWS (NB * NPATCH)    // 3136
#define AROWS 3200              // padded rows for MFMA A-side staging
#define DD (768 * 768)
#define DH (768 * 3072)
#define SZL ((long)NROWS * D)   // 2,420,736

typedef unsigned short u16;
typedef __attribute__((ext_vector_type(8))) _Float16 f16x8;
typedef __attribute__((ext_vector_type(4))) float f32x4;

#define FLAG_ACC 1
#define FLAG_RELU 2
#define FLAG_H16 4

__device__ __forceinline__ u16 f2h(float f) {
    union { _Float16 h; u16 u; } cv;
    cv.h = (_Float16)f;
    return cv.u;
}
__device__ __forceinline__ float h2f(u16 v) {
    union { _Float16 h; u16 u; } cv;
    cv.u = v;
    return (float)cv.h;
}

__device__ __forceinline__ void gld16(const void* g, void* l) {
    __builtin_amdgcn_global_load_lds((const __attribute__((address_space(1))) void*)g,
                                     (__attribute__((address_space(3))) void*)l, 16, 0, 0);
}

// ---------------- single-fp16 MFMA GEMM (patch embed, out-projection) ----------------
__global__ __launch_bounds__(256) void gemm_h16(
    const u16* __restrict__ A, const u16* __restrict__ B,
    void* __restrict__ Cv, const float* __restrict__ bias,
    int M, int N, int K, int lda, int ldbt, int ldc, int flags,
    long sAz, long sBz, long sCz) {
    __shared__ __align__(16) u16 As[128 * 32];
    __shared__ __align__(16) u16 Bs[128 * 32];
    int zz = blockIdx.z;
    A += (long)zz * sAz;
    B += (long)zz * sBz;
    long czoff = (long)zz * sCz;
    int t = threadIdx.x;
    int w = t >> 6, lane = t & 63;
    int lr = lane & 15, lg = lane >> 4;
    int wr = w >> 1, wc = w & 1;
    long row0 = (long)blockIdx.y * 128, col0 = (long)blockIdx.x * 128;

    f32x4 acc[4][4];
#pragma unroll
    for (int i = 0; i < 4; i++)
#pragma unroll
        for (int j = 0; j < 4; j++) acc[i][j] = (f32x4){0.f, 0.f, 0.f, 0.f};

    int c0 = w * 64 + lane;
    int r0s = c0 >> 2, k0s = (((c0 & 3) ^ ((r0s >> 1) & 3)) << 3);
    int c1 = 256 + w * 64 + lane;
    int r1s = c1 >> 2, k1s = (((c1 & 3) ^ ((r1s >> 1) & 3)) << 3);

    for (int kt = 0; kt < K; kt += 32) {
        const u16* AB = A + row0 * lda + kt;
        const u16* BB = B + col0 * ldbt + kt;
        gld16(AB + (long)r0s * lda + k0s, (char*)As + (w * 64) * 16);
        gld16(AB + (long)r1s * lda + k1s, (char*)As + (256 + w * 64) * 16);
        gld16(BB + (long)r0s * ldbt + k0s, (char*)Bs + (w * 64) * 16);
        gld16(BB + (long)r1s * ldbt + k1s, (char*)Bs + (256 + w * 64) * 16);
        __syncthreads();
        f16x8 af[4], bf[4];
#pragma unroll
        for (int mi = 0; mi < 4; mi++) {
            int row = wr * 64 + mi * 16 + lr;
            af[mi] = *(const f16x8*)&As[row * 32 + ((lg ^ ((row >> 1) & 3)) << 3)];
        }
#pragma unroll
        for (int ni = 0; ni < 4; ni++) {
            int row = wc * 64 + ni * 16 + lr;
            bf[ni] = *(const f16x8*)&Bs[row * 32 + ((lg ^ ((row >> 1) & 3)) << 3)];
        }
#pragma unroll
        for (int mi = 0; mi < 4; mi++)
#pragma unroll
            for (int ni = 0; ni < 4; ni++)
                acc[mi][ni] = __builtin_amdgcn_mfma_f32_16x16x32_f16(af[mi], bf[ni], acc[mi][ni], 0, 0, 0);
        __syncthreads();
    }

    long mbase = row0 + wr * 64;
    long nbase = col0 + wc * 64;
#pragma unroll
    for (int mi = 0; mi < 4; mi++) {
#pragma unroll
        for (int r = 0; r < 4; r++) {
            long grow = mbase + mi * 16 + lg * 4 + r;
            if (grow >= M) continue;
#pragma unroll
            for (int ni = 0; ni < 4; ni++) {
                long gcol = nbase + ni * 16 + lr;
                float v = acc[mi][ni][r];
                if (bias) v += bias[gcol];
                if (flags & FLAG_RELU) v = fmaxf(v, 0.f);
                long idx = czoff + grow * ldc + gcol;
                if (flags & FLAG_ACC) ((float*)Cv)[idx] += v;
                else if (flags & FLAG_H16) ((u16*)Cv)[idx] = f2h(v);
                else ((float*)Cv)[idx] = v;
            }
        }
    }
}

// ---------------- fused projection: Q,K (fp16 out) + Hopfield-1 (fp16+relu) ----------------
__global__ __launch_bounds__(256) void fused_proj(
    const u16* __restrict__ A,
    const u16* __restrict__ WQT, const u16* __restrict__ WKT, const u16* __restrict__ XIT,
    u16* __restrict__ Qh, u16* __restrict__ Kh, u16* __restrict__ HH) {
    __shared__ __align__(16) u16 As[128 * 32];
    __shared__ __align__(16) u16 Bs[128 * 32];
    int cx = blockIdx.x;
    const u16* B; int ldc; long col0; int mode;
    if (cx < 6)       { B = WQT; ldc = 768;  col0 = (long)cx * 128;        mode = 0; }
    else if (cx < 12) { B = WKT; ldc = 768;  col0 = (long)(cx - 6) * 128;  mode = 1; }
    else              { B = XIT; ldc = 3072; col0 = (long)(cx - 12) * 128; mode = 2; }
    int t = threadIdx.x;
    int w = t >> 6, lane = t & 63;
    int lr = lane & 15, lg = lane >> 4;
    int wr = w >> 1, wc = w & 1;
    long row0 = (long)blockIdx.y * 128;

    f32x4 acc[4][4];
#pragma unroll
    for (int i = 0; i < 4; i++)
#pragma unroll
        for (int j = 0; j < 4; j++) acc[i][j] = (f32x4){0.f, 0.f, 0.f, 0.f};

    int c0 = w * 64 + lane;
    int r0s = c0 >> 2, k0s = (((c0 & 3) ^ ((r0s >> 1) & 3)) << 3);
    int c1 = 256 + w * 64 + lane;
    int r1s = c1 >> 2, k1s = (((c1 & 3) ^ ((r1s >> 1) & 3)) << 3);

    for (int kt = 0; kt < 768; kt += 32) {
        const u16* AB = A + row0 * 768 + kt;
        const u16* BB = B + col0 * 768 + kt;
        gld16(AB + (long)r0s * 768 + k0s, (char*)As + (w * 64) * 16);
        gld16(AB + (long)r1s * 768 + k1s, (char*)As + (256 + w * 64) * 16);
        gld16(BB + (long)r0s * 768 + k0s, (char*)Bs + (w * 64) * 16);
        gld16(BB + (long)r1s * 768 + k1s, (char*)Bs + (256 + w * 64) * 16);
        __syncthreads();
        f16x8 af[4], bf[4];
#pragma unroll
        for (int mi = 0; mi < 4; mi++) {
            int row = wr * 64 + mi * 16 + lr;
            af[mi] = *(const f16x8*)&As[row * 32 + ((lg ^ ((row >> 1) & 3)) << 3)];
        }
#pragma unroll
        for (int ni = 0; ni < 4; ni++) {
            int row = wc * 64 + ni * 16 + lr;
            bf[ni] = *(const f16x8*)&Bs[row * 32 + ((lg ^ ((row >> 1) & 3)) << 3)];
        }
#pragma unroll
        for (int mi = 0; mi < 4; mi++)
#pragma unroll
            for (int ni = 0; ni < 4; ni++)
                acc[mi][ni] = __builtin_amdgcn_mfma_f32_16x16x32_f16(af[mi], bf[ni], acc[mi][ni], 0, 0, 0);
        __syncthreads();
    }

    long mbase = row0 + wr * 64;
    long nbase = col0 + wc * 64;
#pragma unroll
    for (int mi = 0; mi < 4; mi++) {
#pragma unroll
        for (int r = 0; r < 4; r++) {
            long grow = mbase + mi * 16 + lg * 4 + r;
            if (grow >= NROWS) continue;
#pragma unroll
            for (int ni = 0; ni < 4; ni++) {
                long gcol = nbase + ni * 16 + lr;
                float v = acc[mi][ni][r];
                long idx = grow * ldc + gcol;
                if (mode == 0)      Qh[idx] = f2h(v);
                else if (mode == 1) Kh[idx] = f2h(v);
                else                HH[idx] = f2h(fmaxf(v, 0.f));
            }
        }
    }
}

// ---------------- fused accumulate GEMM: 6 split-K partials -> fp16 slabs ----------------
__global__ __launch_bounds__(256) void gemm_h16_fused(
    const u16* __restrict__ G1, const u16* __restrict__ G2, const u16* __restrict__ HH,
    const u16* __restrict__ WQ, const u16* __restrict__ WK, const u16* __restrict__ XB,
    u16* __restrict__ part) {
    __shared__ __align__(16) u16 As[128 * 32];
    __shared__ __align__(16) u16 Bs[128 * 32];
    int zz = blockIdx.z;
    const u16* A; const u16* B; int lda; int K0;
    if (zz == 0)      { A = G1; B = WQ; lda = 768;  K0 = 0; }
    else if (zz == 1) { A = G2; B = WK; lda = 768;  K0 = 0; }
    else              { A = HH; B = XB; lda = 3072; K0 = (zz - 2) * 768; }
    u16* C = part + (long)zz * SZL;

    int t = threadIdx.x;
    int w = t >> 6, lane = t & 63;
    int lr = lane & 15, lg = lane >> 4;
    int wr = w >> 1, wc = w & 1;
    long row0 = (long)blockIdx.y * 128, col0 = (long)blockIdx.x * 128;

    f32x4 acc[4][4];
#pragma unroll
    for (int i = 0; i < 4; i++)
#pragma unroll
        for (int j = 0; j < 4; j++) acc[i][j] = (f32x4){0.f, 0.f, 0.f, 0.f};

    int c0 = w * 64 + lane;
    int r0s = c0 >> 2, k0s = (((c0 & 3) ^ ((r0s >> 1) & 3)) << 3);
    int c1 = 256 + w * 64 + lane;
    int r1s = c1 >> 2, k1s = (((c1 & 3) ^ ((r1s >> 1) & 3)) << 3);

    for (int kt = K0; kt < K0 + 768; kt += 32) {
        const u16* AB = A + row0 * lda + kt;
        const u16* BB = B + col0 * (long)lda + kt;
        gld16(AB + (long)r0s * lda + k0s, (char*)As + (w * 64) * 16);
        gld16(AB + (long)r1s * lda + k1s, (char*)As + (256 + w * 64) * 16);
        gld16(BB + (long)r0s * lda + k0s, (char*)Bs + (w * 64) * 16);
        gld16(BB + (long)r1s * lda + k1s, (char*)Bs + (256 + w * 64) * 16);
        __syncthreads();
        f16x8 af[4], bf[4];
#pragma unroll
        for (int mi = 0; mi < 4; mi++) {
            int row = wr * 64 + mi * 16 + lr;
            af[mi] = *(const f16x8*)&As[row * 32 + ((lg ^ ((row >> 1) & 3)) << 3)];
        }
#pragma unroll
        for (int ni = 0; ni < 4; ni++) {
            int row = wc * 64 + ni * 16 + lr;
            bf[ni] = *(const f16x8*)&Bs[row * 32 + ((lg ^ ((row >> 1) & 3)) << 3)];
        }
#pragma unroll
        for (int mi = 0; mi < 4; mi++)
#pragma unroll
            for (int ni = 0; ni < 4; ni++)
                acc[mi][ni] = __builtin_amdgcn_mfma_f32_16x16x32_f16(af[mi], bf[ni], acc[mi][ni], 0, 0, 0);
        __syncthreads();
    }

    long mbase = row0 + wr * 64;
    long nbase = col0 + wc * 64;
#pragma unroll
    for (int mi = 0; mi < 4; mi++) {
#pragma unroll
        for (int r = 0; r < 4; r++) {
            long grow = mbase + mi * 16 + lg * 4 + r;
            if (grow >= NROWS) continue;
#pragma unroll
            for (int ni = 0; ni < 4; ni++) {
                long gcol = nbase + ni * 16 + lr;
                C[grow * D + gcol] = f2h(acc[mi][ni][r]);
            }
        }
    }
}

// ---------------- fused reduce + layernorm: h (+= 6 fp16 slabs) -> LN -> fp16 ----------------
__global__ __launch_bounds__(256) void ln_fuse_kernel(
    float* __restrict__ X, u16* __restrict__ Yh16, const u16* __restrict__ part,
    const float* __restrict__ gamma, const float* __restrict__ beta,
    int compact, int doReduce, int writeBack) {
    int r = blockIdx.x;
    long xrow = compact ? ((long)(r / NPATCH) * NTOK + 1 + (r % NPATCH)) : (long)r;
    float* x = X + xrow * D;
    int t = threadIdx.x;
    float v[3];
    float s = 0.f, ss = 0.f;
#pragma unroll
    for (int i = 0; i < 3; i++) {
        int c = t + 256 * i;
        float val = x[c];
        if (doReduce) {
            long off = xrow * D + c;
            float p01 = h2f(part[off]) + h2f(part[SZL + off]);
            float p23 = h2f(part[2 * SZL + off]) + h2f(part[3 * SZL + off]);
            float p45 = h2f(part[4 * SZL + off]) + h2f(part[5 * SZL + off]);
            val += (p01 + p23) + p45;
            if (writeBack) x[c] = val;
        }
        v[i] = val;
        s += val;
        ss += val * val;
    }
    __shared__ float red[8];
    for (int off = 32; off; off >>= 1) {
        s += __shfl_down(s, off, 64);
        ss += __shfl_down(ss, off, 64);
    }
    int wid = t >> 6, lane = t & 63;
    if (lane == 0) { red[wid] = s; red[4 + wid] = ss; }
    __syncthreads();
    s = red[0] + red[1] + red[2] + red[3];
    ss = red[4] + red[5] + red[6] + red[7];
    float mu = s * (1.f / 768.f);
    float var = ss * (1.f / 768.f) - mu * mu;
    float inv = rsqrtf(var + 1e-5f);
#pragma unroll
    for (int i = 0; i < 3; i++) {
        int c = t + 256 * i;
        float yv = gamma[c] * (v[i] - mu) * inv + beta[c];
        Yh16[(long)r * D + c] = f2h(yv);
    }
}

// ---------------- parallel attention softmax (fp16 Q/K in, fp16 Pt out; grid 192x13) ----------------
__global__ __launch_bounds__(256) void attn_p_kernel(const u16* __restrict__ Q, const u16* __restrict__ K,
                                                     u16* __restrict__ Pt) {
    __shared__ __align__(16) u16 Ks[NTOK][72];
    int bh = blockIdx.x, mt = blockIdx.y;
    int b = bh / NH, h = bh % NH;
    int t = threadIdx.x;
    const u16* Kb = K + (long)b * NTOK * D + h * HD;
    for (int i = t; i < NTOK * 8; i += 256) {
        int n = i >> 3, c8 = (i & 7) << 3;
        *(uint4*)&Ks[n][c8] = *(const uint4*)(Kb + (long)n * D + c8);
    }
    __syncthreads();
    int ql = t >> 4, l16 = t & 15;
    int m = mt * 16 + ql;
    int mr = m < NTOK ? m : NTOK - 1;
    const u16* Qrow = Q + (long)(b * NTOK + mr) * D + h * HD;
    float q[64];
#pragma unroll
    for (int k = 0; k < 64; k += 8) {
        f16x8 v = *(const f16x8*)(Qrow + k);
#pragma unroll
        for (int j = 0; j < 8; j++) q[k + j] = (float)v[j];
    }
    float s[13];
    float mx = -1e30f;
#pragma unroll
    for (int i = 0; i < 13; i++) {
        int n = i * 16 + l16;
        const u16* kr = Ks[n < NTOK ? n : 0];
        float a0 = 0.f, a1 = 0.f, a2 = 0.f, a3 = 0.f;
#pragma unroll
        for (int k = 0; k < 64; k += 8) {
            f16x8 kv = *(const f16x8*)&kr[k];
            a0 += (float)kv[0] * q[k]     + (float)kv[4] * q[k + 4];
            a1 += (float)kv[1] * q[k + 1] + (float)kv[5] * q[k + 5];
            a2 += (float)kv[2] * q[k + 2] + (float)kv[6] * q[k + 6];
            a3 += (float)kv[3] * q[k + 3] + (float)kv[7] * q[k + 7];
        }
        float sv = ((a0 + a1) + (a2 + a3)) * BETA_F;
        s[i] = (n < NTOK) ? sv : -1e30f;
        mx = fmaxf(mx, s[i]);
    }
    mx = fmaxf(mx, __shfl_xor(mx, 1, 64));
    mx = fmaxf(mx, __shfl_xor(mx, 2, 64));
    mx = fmaxf(mx, __shfl_xor(mx, 4, 64));
    mx = fmaxf(mx, __shfl_xor(mx, 8, 64));
    float ssum = 0.f;
#pragma unroll
    for (int i = 0; i < 13; i++) {
        float e = (s[i] > -1e29f) ? __expf(s[i] - mx) : 0.f;
        s[i] = e;
        ssum += e;
    }
    ssum += __shfl_xor(ssum, 1, 64);
    ssum += __shfl_xor(ssum, 2, 64);
    ssum += __shfl_xor(ssum, 4, 64);
    ssum += __shfl_xor(ssum, 8, 64);
    float inv = 1.f / ssum;
    if (m < NTOK) {
        u16* PtB = Pt + (long)bh * PBH;
#pragma unroll
        for (int i = 0; i < 13; i++) {
            int n = i * 16 + l16;
            PtB[(long)m * PLD + n] = (n < NTOK) ? f2h(s[i] * inv) : (u16)0;
        }
    }
}

// ---------------- attention grads: G1 (A normal) + G2 (A transposed); fp16 Pt + fp16 Q/K ----------------
__global__ __launch_bounds__(256) void attn_g_kernel(
    const u16* __restrict__ Pt, const u16* __restrict__ Qh, const u16* __restrict__ Kh,
    u16* __restrict__ G1, u16* __restrict__ G2) {
    __shared__ float As[16][68];
    __shared__ float Bs[16][68];
    int z = blockIdx.z;
    int which = z / 192, bh = z - which * 192;
    int b = bh / NH, h = bh % NH;
    const u16* A = Pt + (long)bh * PBH;
    const u16* B = (which ? Qh : Kh) + (long)b * NTOK * D + h * HD;
    u16* G = which ? G2 : G1;

    int t = threadIdx.x;
    int tx = t & 15, ty = t >> 4;
    int row0 = blockIdx.y * 64;

    float acc[4][4] = {};

    for (int kt = 0; kt < NTOK; kt += 16) {
        if (which == 0) {
            int r = t >> 2, c4 = (t & 3) << 2;
            int gr = row0 + r, gk = kt + c4;
            float4 v = make_float4(0.f, 0.f, 0.f, 0.f);
            if (gr < NTOK) {
                ushort4 u = *(const ushort4*)(A + (long)gr * PLD + gk);
                v = make_float4(h2f(u.x), h2f(u.y), h2f(u.z), h2f(u.w));
            }
            As[c4 + 0][r] = v.x; As[c4 + 1][r] = v.y; As[c4 + 2][r] = v.z; As[c4 + 3][r] = v.w;
        } else {
            int rr = t >> 4, c4 = (t & 15) << 2;
            int gk = kt + rr, gc = row0 + c4;
            float4 v = make_float4(0.f, 0.f, 0.f, 0.f);
            if (gk < NTOK && gc + 3 < PLD) {
                ushort4 u = *(const ushort4*)(A + (long)gk * PLD + gc);
                v = make_float4(h2f(u.x), h2f(u.y), h2f(u.z), h2f(u.w));
            }
            As[rr][c4 + 0] = v.x; As[rr][c4 + 1] = v.y; As[rr][c4 + 2] = v.z; As[rr][c4 + 3] = v.w;
        }
        {
            int r = t >> 4, c4 = (t & 15) << 2;
            int gk = kt + r;
            float4 v = make_float4(0.f, 0.f, 0.f, 0.f);
            if (gk < NTOK) {
                ushort4 u = *(const ushort4*)(B + (long)gk * D + c4);
                v = make_float4(h2f(u.x), h2f(u.y), h2f(u.z), h2f(u.w));
            }
            Bs[r][c4 + 0] = v.x; Bs[r][c4 + 1] = v.y; Bs[r][c4 + 2] = v.z; Bs[r][c4 + 3] = v.w;
        }
        __syncthreads();
#pragma unroll
        for (int kk = 0; kk < 16; kk++) {
            float av[4], bv[4];
#pragma unroll
            for (int i = 0; i < 4; i++) av[i] = As[kk][ty * 4 + i];
#pragma unroll
            for (int j = 0; j < 4; j++) bv[j] = Bs[kk][tx * 4 + j];
#pragma unroll
            for (int i = 0; i < 4; i++)
#pragma unroll
                for (int j = 0; j < 4; j++) acc[i][j] += av[i] * bv[j];
        }
        __syncthreads();
    }
#pragma unroll
    for (int i = 0; i < 4; i++) {
        int gr = row0 + ty * 4 + i;
        if (gr >= NTOK) continue;
#pragma unroll
        for (int j = 0; j < 4; j++) {
            int gc = tx * 4 + j;
            long idx = ((long)(b * NTOK + gr)) * D + h * HD + gc;
            G[idx] = f2h(acc[i][j]);
        }
    }
}

// ================= setup pieces =================

__global__ __launch_bounds__(256) void patchify_kernel(const float* __restrict__ x, u16* __restrict__ tok) {
    int idx = blockIdx.x * 256 + threadIdx.x;
    const int total = NB * NPATCH * D;
    if (idx >= total) return;
    int d = idx % D;
    int p = (idx / D) % NPATCH;
    int b = idx / (D * NPATCH);
    int c = d >> 8;
    int pi = (d >> 4) & 15;
    int pj = d & 15;
    int hp = p / 14, wp = p % 14;
    int row = hp * 16 + pi, col = wp * 16 + pj;
    tok[idx] = f2h(x[(((long)b * 3 + c) * 224 + row) * 224 + col]);
}

__global__ __launch_bounds__(256) void cls_pos_kernel(float* __restrict__ h, const float* __restrict__ cls,
                                                      const float* __restrict__ pos) {
    int idx = blockIdx.x * 256 + threadIdx.x;
    const int total = NB * NTOK * D;
    if (idx >= total) return;
    int d = idx % D;
    int n = (idx / D) % NTOK;
    float v = pos[n * D + d];
    if (n == 0) h[idx] = cls[d] + v;
    else        h[idx] = h[idx] + v;
}

__global__ __launch_bounds__(256) void wcat_kernel(const float* __restrict__ w, float* __restrict__ Wm) {
    int idx = blockIdx.x * 256 + threadIdx.x;
    const int total = NH * D * HD;
    if (idx >= total) return;
    int k = idx & 63;
    int d = (idx >> 6) % D;
    int hh = idx / (D * HD);
    Wm[d * D + hh * HD + k] = w[idx];
}

// ---------------- COALESCED tiled transpose prep: dst[c][r] = f2h(src[r][c]) ----------------
__global__ __launch_bounds__(256) void prep_transpose_h(const float* __restrict__ src,
                                                        u16* __restrict__ dst, int R, int C) {
    __shared__ float tile[32][33];
    int c0 = blockIdx.x * 32, r0 = blockIdx.y * 32;
    int tx = threadIdx.x & 31, ty = threadIdx.x >> 5;
    for (int i = ty; i < 32; i += 8)
        tile[i][tx] = src[(long)(r0 + i) * C + c0 + tx];
    __syncthreads();
    for (int i = ty; i < 32; i += 8)
        dst[(long)(c0 + i) * R + r0 + tx] = f2h(tile[tx][i]);
}
__global__ __launch_bounds__(256) void prep_convert_h(const float* __restrict__ src,
                                                      u16* __restrict__ dst, int n) {
    int idx = blockIdx.x * 256 + threadIdx.x;
    if (idx >= n) return;
    dst[idx] = f2h(src[idx]);
}

extern "C" void kernel_launch(void* const* d_in, const int* in_sizes, int n_in,
                              void* d_out, int out_size, void* d_ws, size_t ws_size,
                              hipStream_t stream) {
    const float* x        = (const float*)d_in[0];
    const float* patch_w  = (const float*)d_in[1];
    const float* patch_b  = (const float*)d_in[2];
    const float* cls_tok  = (const float*)d_in[3];
    const float* pos_emb  = (const float*)d_in[4];
    const float* ln_gamma = (const float*)d_in[5];
    const float* ln_beta  = (const float*)d_in[6];
    const float* wq       = (const float*)d_in[7];
    const float* wk       = (const float*)d_in[8];
    const float* xi       = (const float*)d_in[9];
    const float* out_gamma= (const float*)d_in[10];
    const float* out_beta = (const float*)d_in[11];
    const float* out_w    = (const float*)d_in[12];
    const float* out_b    = (const float*)d_in[13];
    float* out = (float*)d_out;

    float* ws = (float*)d_ws;
    const long SZ = SZL;
    const long AR = (long)AROWS * D;
    float* h  = ws;
    u16* gh16    = (u16*)(ws + SZ);
    u16* Qh16    = gh16 + AR;
    u16* Kh16    = Qh16 + AR;
    u16* WmQTh16 = Kh16 + AR;
    u16* WmKTh16 = WmQTh16 + DD;
    u16* WmQh16  = WmKTh16 + DD;
    u16* WmKh16  = WmQh16 + DD;
    u16* xiTh16  = WmKh16 + DD;
    u16* xibh16  = xiTh16 + DH;
    u16* G1h16   = xibh16 + DH;
    u16* G2h16   = G1h16 + AR;
    u16* HH16    = G2h16 + AR;
    u16* owTh16  = HH16 + (long)AROWS * HOP;
    u16* pwTh16  = owTh16 + DD;
    // shared region (sequenced aliasing): part (6*SZ u16) | Pt (192*PBH u16) | tok16 (setup)
    char* R1c = (char*)(pwTh16 + DD);
    u16* Pt16   = (u16*)R1c;
    u16* part16 = (u16*)R1c;
    u16* tok16  = (u16*)R1c;
    float* WmQ  = (float*)(R1c + (size_t)6 * SZ * 2);   // setup-only f32 scratch
    float* WmK  = WmQ + DD;

    // ---- setup ----
    patchify_kernel<<<(NB * NPATCH * D + 255) / 256, 256, 0, stream>>>(x, tok16);
    wcat_kernel<<<(NH * D * HD + 255) / 256, 256, 0, stream>>>(wq, WmQ);
    wcat_kernel<<<(NH * D * HD + 255) / 256, 256, 0, stream>>>(wk, WmK);
    prep_transpose_h<<<dim3(24, 24), 256, 0, stream>>>(WmQ, WmQTh16, 768, 768);
    prep_transpose_h<<<dim3(24, 24), 256, 0, stream>>>(WmK, WmKTh16, 768, 768);
    prep_convert_h<<<(DD + 255) / 256, 256, 0, stream>>>(WmQ, WmQh16, DD);
    prep_convert_h<<<(DD + 255) / 256, 256, 0, stream>>>(WmK, WmKh16, DD);
    prep_transpose_h<<<dim3(96, 24), 256, 0, stream>>>(xi, xiTh16, 768, HOP);
    prep_convert_h<<<(DH + 255) / 256, 256, 0, stream>>>(xi, xibh16, DH);
    prep_transpose_h<<<dim3(24, 24), 256, 0, stream>>>(out_w, owTh16, 768, 768);
    prep_transpose_h<<<dim3(24, 24), 256, 0, stream>>>(patch_w, pwTh16, 768, 768);
    // patch embed via fp16 MFMA: h rows 1..196 per batch (f32 out + f32 bias)
    gemm_h16<<<dim3(6, 2, NB), 256, 0, stream>>>(
        tok16, pwTh16, h + D, patch_b,
        NPATCH, D, D, D, D, D, 0,
        (long)NPATCH * D, 0, (long)NTOK * D);
    cls_pos_kernel<<<(NB * NTOK * D + 255) / 256, 256, 0, stream>>>(h, cls_tok, pos_emb);

    for (int step = 0; step < TSTEPS; step++) {
        ln_fuse_kernel<<<NROWS, 256, 0, stream>>>(h, gh16, part16, ln_gamma, ln_beta,
                                                  0, step > 0 ? 1 : 0, 1);
        fused_proj<<<dim3(36, 25), 256, 0, stream>>>(gh16, WmQTh16, WmKTh16, xiTh16, Qh16, Kh16, HH16);
        attn_p_kernel<<<dim3(192, 13), 256, 0, stream>>>(Qh16, Kh16, Pt16);
        attn_g_kernel<<<dim3(1, 4, 384), 256, 0, stream>>>(Pt16, Qh16, Kh16, G1h16, G2h16);
        gemm_h16_fused<<<dim3(6, 25, 6), 256, 0, stream>>>(
            G1h16, G2h16, HH16, WmQh16, WmKh16, xibh16, part16);
    }

    // ---- final: reduce + LN (compact) -> fp16, then out projection (fp16 MFMA) ----
    ln_fuse_kernel<<<NPROWS, 256, 0, stream>>>(h, gh16, part16, out_gamma, out_beta, 1, 1, 0);
    gemm_h16<<<dim3(6, 25, 1), 256, 0, stream>>>(
        gh16, owTh16, out, out_b, NPROWS, D, D, D, D, D, 0, 0, 0, 0);
}

// Round 18
// 1150.860 us; speedup vs baseline: 1.6051x; 1.0104x over previous
//
#include <hip/hip_runtime.h>

#define NB 16
#define NTOK 197
#define NPATCH 196
#define D 768
#define NH 12
#define HD 64
#define HOP 3072
#define TSTEPS 6
#define BETA_F 0.125f
#define PLD 208                 // Pt leading dim (fp16)
#define PBH (NTOK * PLD)        // 40976
#define NROWS (NB * NTOK)       // 3152
#define NPROWS (NB * NPATCH)    // 3136
#define AROWS 3200              // padded rows for MFMA A-side staging
#define DD (768 * 768)
#define DH (768 * 3072)
#define SZL ((long)NROWS * D)   // 2,420,736

typedef unsigned short u16;
typedef __attribute__((ext_vector_type(8))) _Float16 f16x8;
typedef __attribute__((ext_vector_type(4))) float f32x4;

#define FLAG_ACC 1
#define FLAG_RELU 2
#define FLAG_H16 4

__device__ __forceinline__ u16 f2h(float f) {
    union { _Float16 h; u16 u; } cv;
    cv.h = (_Float16)f;
    return cv.u;
}
__device__ __forceinline__ float h2f(u16 v) {
    union { _Float16 h; u16 u; } cv;
    cv.u = v;
    return (float)cv.h;
}

__device__ __forceinline__ void gld16(const void* g, void* l) {
    __builtin_amdgcn_global_load_lds((const __attribute__((address_space(1))) void*)g,
                                     (__attribute__((address_space(3))) void*)l, 16, 0, 0);
}

// bijective XCD swizzle for nwg=900 on 8 XCDs (m204): chunks 4x113 + 4x112.
__device__ __forceinline__ int xcd_swz900(int bid) {
    int xcd = bid & 7, k = bid >> 3;
    return (xcd < 4 ? xcd * 113 : 452 + (xcd - 4) * 112) + k;
}

// ---------------- single-fp16 MFMA GEMM (patch embed, out-projection) ----------------
__global__ __launch_bounds__(256) void gemm_h16(
    const u16* __restrict__ A, const u16* __restrict__ B,
    void* __restrict__ Cv, const float* __restrict__ bias,
    int M, int N, int K, int lda, int ldbt, int ldc, int flags,
    long sAz, long sBz, long sCz) {
    __shared__ __align__(16) u16 As[128 * 32];
    __shared__ __align__(16) u16 Bs[128 * 32];
    int zz = blockIdx.z;
    A += (long)zz * sAz;
    B += (long)zz * sBz;
    long czoff = (long)zz * sCz;
    int t = threadIdx.x;
    int w = t >> 6, lane = t & 63;
    int lr = lane & 15, lg = lane >> 4;
    int wr = w >> 1, wc = w & 1;
    long row0 = (long)blockIdx.y * 128, col0 = (long)blockIdx.x * 128;

    f32x4 acc[4][4];
#pragma unroll
    for (int i = 0; i < 4; i++)
#pragma unroll
        for (int j = 0; j < 4; j++) acc[i][j] = (f32x4){0.f, 0.f, 0.f, 0.f};

    int c0 = w * 64 + lane;
    int r0s = c0 >> 2, k0s = (((c0 & 3) ^ ((r0s >> 1) & 3)) << 3);
    int c1 = 256 + w * 64 + lane;
    int r1s = c1 >> 2, k1s = (((c1 & 3) ^ ((r1s >> 1) & 3)) << 3);

    for (int kt = 0; kt < K; kt += 32) {
        const u16* AB = A + row0 * lda + kt;
        const u16* BB = B + col0 * ldbt + kt;
        gld16(AB + (long)r0s * lda + k0s, (char*)As + (w * 64) * 16);
        gld16(AB + (long)r1s * lda + k1s, (char*)As + (256 + w * 64) * 16);
        gld16(BB + (long)r0s * ldbt + k0s, (char*)Bs + (w * 64) * 16);
        gld16(BB + (long)r1s * ldbt + k1s, (char*)Bs + (256 + w * 64) * 16);
        __syncthreads();
        f16x8 af[4], bf[4];
#pragma unroll
        for (int mi = 0; mi < 4; mi++) {
            int row = wr * 64 + mi * 16 + lr;
            af[mi] = *(const f16x8*)&As[row * 32 + ((lg ^ ((row >> 1) & 3)) << 3)];
        }
#pragma unroll
        for (int ni = 0; ni < 4; ni++) {
            int row = wc * 64 + ni * 16 + lr;
            bf[ni] = *(const f16x8*)&Bs[row * 32 + ((lg ^ ((row >> 1) & 3)) << 3)];
        }
#pragma unroll
        for (int mi = 0; mi < 4; mi++)
#pragma unroll
            for (int ni = 0; ni < 4; ni++)
                acc[mi][ni] = __builtin_amdgcn_mfma_f32_16x16x32_f16(af[mi], bf[ni], acc[mi][ni], 0, 0, 0);
        __syncthreads();
    }

    long mbase = row0 + wr * 64;
    long nbase = col0 + wc * 64;
#pragma unroll
    for (int mi = 0; mi < 4; mi++) {
#pragma unroll
        for (int r = 0; r < 4; r++) {
            long grow = mbase + mi * 16 + lg * 4 + r;
            if (grow >= M) continue;
#pragma unroll
            for (int ni = 0; ni < 4; ni++) {
                long gcol = nbase + ni * 16 + lr;
                float v = acc[mi][ni][r];
                if (bias) v += bias[gcol];
                if (flags & FLAG_RELU) v = fmaxf(v, 0.f);
                long idx = czoff + grow * ldc + gcol;
                if (flags & FLAG_ACC) ((float*)Cv)[idx] += v;
                else if (flags & FLAG_H16) ((u16*)Cv)[idx] = f2h(v);
                else ((float*)Cv)[idx] = v;
            }
        }
    }
}

// ---------------- fused projection: Q,K (fp16 out) + Hopfield-1 (fp16+relu); XCD-swizzled 1D grid 900 ----------------
__global__ __launch_bounds__(256) void fused_proj(
    const u16* __restrict__ A,
    const u16* __restrict__ WQT, const u16* __restrict__ WKT, const u16* __restrict__ XIT,
    u16* __restrict__ Qh, u16* __restrict__ Kh, u16* __restrict__ HH) {
    __shared__ __align__(16) u16 As[128 * 32];
    __shared__ __align__(16) u16 Bs[128 * 32];
    int lid = xcd_swz900(blockIdx.x);
    int cx = lid % 36, by = lid / 36;
    const u16* B; int ldc; long col0; int mode;
    if (cx < 6)       { B = WQT; ldc = 768;  col0 = (long)cx * 128;        mode = 0; }
    else if (cx < 12) { B = WKT; ldc = 768;  col0 = (long)(cx - 6) * 128;  mode = 1; }
    else              { B = XIT; ldc = 3072; col0 = (long)(cx - 12) * 128; mode = 2; }
    int t = threadIdx.x;
    int w = t >> 6, lane = t & 63;
    int lr = lane & 15, lg = lane >> 4;
    int wr = w >> 1, wc = w & 1;
    long row0 = (long)by * 128;

    f32x4 acc[4][4];
#pragma unroll
    for (int i = 0; i < 4; i++)
#pragma unroll
        for (int j = 0; j < 4; j++) acc[i][j] = (f32x4){0.f, 0.f, 0.f, 0.f};

    int c0 = w * 64 + lane;
    int r0s = c0 >> 2, k0s = (((c0 & 3) ^ ((r0s >> 1) & 3)) << 3);
    int c1 = 256 + w * 64 + lane;
    int r1s = c1 >> 2, k1s = (((c1 & 3) ^ ((r1s >> 1) & 3)) << 3);

    for (int kt = 0; kt < 768; kt += 32) {
        const u16* AB = A + row0 * 768 + kt;
        const u16* BB = B + col0 * 768 + kt;
        gld16(AB + (long)r0s * 768 + k0s, (char*)As + (w * 64) * 16);
        gld16(AB + (long)r1s * 768 + k1s, (char*)As + (256 + w * 64) * 16);
        gld16(BB + (long)r0s * 768 + k0s, (char*)Bs + (w * 64) * 16);
        gld16(BB + (long)r1s * 768 + k1s, (char*)Bs + (256 + w * 64) * 16);
        __syncthreads();
        f16x8 af[4], bf[4];
#pragma unroll
        for (int mi = 0; mi < 4; mi++) {
            int row = wr * 64 + mi * 16 + lr;
            af[mi] = *(const f16x8*)&As[row * 32 + ((lg ^ ((row >> 1) & 3)) << 3)];
        }
#pragma unroll
        for (int ni = 0; ni < 4; ni++) {
            int row = wc * 64 + ni * 16 + lr;
            bf[ni] = *(const f16x8*)&Bs[row * 32 + ((lg ^ ((row >> 1) & 3)) << 3)];
        }
#pragma unroll
        for (int mi = 0; mi < 4; mi++)
#pragma unroll
            for (int ni = 0; ni < 4; ni++)
                acc[mi][ni] = __builtin_amdgcn_mfma_f32_16x16x32_f16(af[mi], bf[ni], acc[mi][ni], 0, 0, 0);
        __syncthreads();
    }

    long mbase = row0 + wr * 64;
    long nbase = col0 + wc * 64;
#pragma unroll
    for (int mi = 0; mi < 4; mi++) {
#pragma unroll
        for (int r = 0; r < 4; r++) {
            long grow = mbase + mi * 16 + lg * 4 + r;
            if (grow >= NROWS) continue;
#pragma unroll
            for (int ni = 0; ni < 4; ni++) {
                long gcol = nbase + ni * 16 + lr;
                float v = acc[mi][ni][r];
                long idx = grow * ldc + gcol;
                if (mode == 0)      Qh[idx] = f2h(v);
                else if (mode == 1) Kh[idx] = f2h(v);
                else                HH[idx] = f2h(fmaxf(v, 0.f));
            }
        }
    }
}

// ---------------- fused accumulate GEMM: 6 split-K partials -> fp16 slabs; XCD-swizzled 1D grid 900 ----------------
__global__ __launch_bounds__(256) void gemm_h16_fused(
    const u16* __restrict__ G1, const u16* __restrict__ G2, const u16* __restrict__ HH,
    const u16* __restrict__ WQ, const u16* __restrict__ WK, const u16* __restrict__ XB,
    u16* __restrict__ part) {
    __shared__ __align__(16) u16 As[128 * 32];
    __shared__ __align__(16) u16 Bs[128 * 32];
    int lid = xcd_swz900(blockIdx.x);
    int bx = lid % 6, by = (lid / 6) % 25, zz = lid / 150;
    const u16* A; const u16* B; int lda; int K0;
    if (zz == 0)      { A = G1; B = WQ; lda = 768;  K0 = 0; }
    else if (zz == 1) { A = G2; B = WK; lda = 768;  K0 = 0; }
    else              { A = HH; B = XB; lda = 3072; K0 = (zz - 2) * 768; }
    u16* C = part + (long)zz * SZL;

    int t = threadIdx.x;
    int w = t >> 6, lane = t & 63;
    int lr = lane & 15, lg = lane >> 4;
    int wr = w >> 1, wc = w & 1;
    long row0 = (long)by * 128, col0 = (long)bx * 128;

    f32x4 acc[4][4];
#pragma unroll
    for (int i = 0; i < 4; i++)
#pragma unroll
        for (int j = 0; j < 4; j++) acc[i][j] = (f32x4){0.f, 0.f, 0.f, 0.f};

    int c0 = w * 64 + lane;
    int r0s = c0 >> 2, k0s = (((c0 & 3) ^ ((r0s >> 1) & 3)) << 3);
    int c1 = 256 + w * 64 + lane;
    int r1s = c1 >> 2, k1s = (((c1 & 3) ^ ((r1s >> 1) & 3)) << 3);

    for (int kt = K0; kt < K0 + 768; kt += 32) {
        const u16* AB = A + row0 * lda + kt;
        const u16* BB = B + col0 * (long)lda + kt;
        gld16(AB + (long)r0s * lda + k0s, (char*)As + (w * 64) * 16);
        gld16(AB + (long)r1s * lda + k1s, (char*)As + (256 + w * 64) * 16);
        gld16(BB + (long)r0s * lda + k0s, (char*)Bs + (w * 64) * 16);
        gld16(BB + (long)r1s * lda + k1s, (char*)Bs + (256 + w * 64) * 16);
        __syncthreads();
        f16x8 af[4], bf[4];
#pragma unroll
        for (int mi = 0; mi < 4; mi++) {
            int row = wr * 64 + mi * 16 + lr;
            af[mi] = *(const f16x8*)&As[row * 32 + ((lg ^ ((row >> 1) & 3)) << 3)];
        }
#pragma unroll
        for (int ni = 0; ni < 4; ni++) {
            int row = wc * 64 + ni * 16 + lr;
            bf[ni] = *(const f16x8*)&Bs[row * 32 + ((lg ^ ((row >> 1) & 3)) << 3)];
        }
#pragma unroll
        for (int mi = 0; mi < 4; mi++)
#pragma unroll
            for (int ni = 0; ni < 4; ni++)
                acc[mi][ni] = __builtin_amdgcn_mfma_f32_16x16x32_f16(af[mi], bf[ni], acc[mi][ni], 0, 0, 0);
        __syncthreads();
    }

    long mbase = row0 + wr * 64;
    long nbase = col0 + wc * 64;
#pragma unroll
    for (int mi = 0; mi < 4; mi++) {
#pragma unroll
        for (int r = 0; r < 4; r++) {
            long grow = mbase + mi * 16 + lg * 4 + r;
            if (grow >= NROWS) continue;
#pragma unroll
            for (int ni = 0; ni < 4; ni++) {
                long gcol = nbase + ni * 16 + lr;
                C[grow * D + gcol] = f2h(acc[mi][ni][r]);
            }
        }
    }
}

// ---------------- fused reduce + layernorm: h (+= 6 fp16 slabs) -> LN -> fp16 ----------------
__global__ __launch_bounds__(256) void ln_fuse_kernel(
    float* __restrict__ X, u16* __restrict__ Yh16, const u16* __restrict__ part,
    const float* __restrict__ gamma, const float* __restrict__ beta,
    int compact, int doReduce, int writeBack) {
    int r = blockIdx.x;
    long xrow = compact ? ((long)(r / NPATCH) * NTOK + 1 + (r % NPATCH)) : (long)r;
    float* x = X + xrow * D;
    int t = threadIdx.x;
    float v[3];
    float s = 0.f, ss = 0.f;
#pragma unroll
    for (int i = 0; i < 3; i++) {
        int c = t + 256 * i;
        float val = x[c];
        if (doReduce) {
            long off = xrow * D + c;
            float p01 = h2f(part[off]) + h2f(part[SZL + off]);
            float p23 = h2f(part[2 * SZL + off]) + h2f(part[3 * SZL + off]);
            float p45 = h2f(part[4 * SZL + off]) + h2f(part[5 * SZL + off]);
            val += (p01 + p23) + p45;
            if (writeBack) x[c] = val;
        }
        v[i] = val;
        s += val;
        ss += val * val;
    }
    __shared__ float red[8];
    for (int off = 32; off; off >>= 1) {
        s += __shfl_down(s, off, 64);
        ss += __shfl_down(ss, off, 64);
    }
    int wid = t >> 6, lane = t & 63;
    if (lane == 0) { red[wid] = s; red[4 + wid] = ss; }
    __syncthreads();
    s = red[0] + red[1] + red[2] + red[3];
    ss = red[4] + red[5] + red[6] + red[7];
    float mu = s * (1.f / 768.f);
    float var = ss * (1.f / 768.f) - mu * mu;
    float inv = rsqrtf(var + 1e-5f);
#pragma unroll
    for (int i = 0; i < 3; i++) {
        int c = t + 256 * i;
        float yv = gamma[c] * (v[i] - mu) * inv + beta[c];
        Yh16[(long)r * D + c] = f2h(yv);
    }
}

// ---------------- parallel attention softmax (fp16 Q/K in, fp16 Pt out; grid 192x13) ----------------
__global__ __launch_bounds__(256) void attn_p_kernel(const u16* __restrict__ Q, const u16* __restrict__ K,
                                                     u16* __restrict__ Pt) {
    __shared__ __align__(16) u16 Ks[NTOK][72];
    int bh = blockIdx.x, mt = blockIdx.y;
    int b = bh / NH, h = bh % NH;
    int t = threadIdx.x;
    const u16* Kb = K + (long)b * NTOK * D + h * HD;
    for (int i = t; i < NTOK * 8; i += 256) {
        int n = i >> 3, c8 = (i & 7) << 3;
        *(uint4*)&Ks[n][c8] = *(const uint4*)(Kb + (long)n * D + c8);
    }
    __syncthreads();
    int ql = t >> 4, l16 = t & 15;
    int m = mt * 16 + ql;
    int mr = m < NTOK ? m : NTOK - 1;
    const u16* Qrow = Q + (long)(b * NTOK + mr) * D + h * HD;
    float q[64];
#pragma unroll
    for (int k = 0; k < 64; k += 8) {
        f16x8 v = *(const f16x8*)(Qrow + k);
#pragma unroll
        for (int j = 0; j < 8; j++) q[k + j] = (float)v[j];
    }
    float s[13];
    float mx = -1e30f;
#pragma unroll
    for (int i = 0; i < 13; i++) {
        int n = i * 16 + l16;
        const u16* kr = Ks[n < NTOK ? n : 0];
        float a0 = 0.f, a1 = 0.f, a2 = 0.f, a3 = 0.f;
#pragma unroll
        for (int k = 0; k < 64; k += 8) {
            f16x8 kv = *(const f16x8*)&kr[k];
            a0 += (float)kv[0] * q[k]     + (float)kv[4] * q[k + 4];
            a1 += (float)kv[1] * q[k + 1] + (float)kv[5] * q[k + 5];
            a2 += (float)kv[2] * q[k + 2] + (float)kv[6] * q[k + 6];
            a3 += (float)kv[3] * q[k + 3] + (float)kv[7] * q[k + 7];
        }
        float sv = ((a0 + a1) + (a2 + a3)) * BETA_F;
        s[i] = (n < NTOK) ? sv : -1e30f;
        mx = fmaxf(mx, s[i]);
    }
    mx = fmaxf(mx, __shfl_xor(mx, 1, 64));
    mx = fmaxf(mx, __shfl_xor(mx, 2, 64));
    mx = fmaxf(mx, __shfl_xor(mx, 4, 64));
    mx = fmaxf(mx, __shfl_xor(mx, 8, 64));
    float ssum = 0.f;
#pragma unroll
    for (int i = 0; i < 13; i++) {
        float e = (s[i] > -1e29f) ? __expf(s[i] - mx) : 0.f;
        s[i] = e;
        ssum += e;
    }
    ssum += __shfl_xor(ssum, 1, 64);
    ssum += __shfl_xor(ssum, 2, 64);
    ssum += __shfl_xor(ssum, 4, 64);
    ssum += __shfl_xor(ssum, 8, 64);
    float inv = 1.f / ssum;
    if (m < NTOK) {
        u16* PtB = Pt + (long)bh * PBH;
#pragma unroll
        for (int i = 0; i < 13; i++) {
            int n = i * 16 + l16;
            PtB[(long)m * PLD + n] = (n < NTOK) ? f2h(s[i] * inv) : (u16)0;
        }
    }
}

// ---------------- attention grads: G1 (A normal) + G2 (A transposed); fp16 Pt + fp16 Q/K ----------------
__global__ __launch_bounds__(256) void attn_g_kernel(
    const u16* __restrict__ Pt, const u16* __restrict__ Qh, const u16* __restrict__ Kh,
    u16* __restrict__ G1, u16* __restrict__ G2) {
    __shared__ float As[16][68];
    __shared__ float Bs[16][68];
    int z = blockIdx.z;
    int which = z / 192, bh = z - which * 192;
    int b = bh / NH, h = bh % NH;
    const u16* A = Pt + (long)bh * PBH;
    const u16* B = (which ? Qh : Kh) + (long)b * NTOK * D + h * HD;
    u16* G = which ? G2 : G1;

    int t = threadIdx.x;
    int tx = t & 15, ty = t >> 4;
    int row0 = blockIdx.y * 64;

    float acc[4][4] = {};

    for (int kt = 0; kt < NTOK; kt += 16) {
        if (which == 0) {
            int r = t >> 2, c4 = (t & 3) << 2;
            int gr = row0 + r, gk = kt + c4;
            float4 v = make_float4(0.f, 0.f, 0.f, 0.f);
            if (gr < NTOK) {
                ushort4 u = *(const ushort4*)(A + (long)gr * PLD + gk);
                v = make_float4(h2f(u.x), h2f(u.y), h2f(u.z), h2f(u.w));
            }
            As[c4 + 0][r] = v.x; As[c4 + 1][r] = v.y; As[c4 + 2][r] = v.z; As[c4 + 3][r] = v.w;
        } else {
            int rr = t >> 4, c4 = (t & 15) << 2;
            int gk = kt + rr, gc = row0 + c4;
            float4 v = make_float4(0.f, 0.f, 0.f, 0.f);
            if (gk < NTOK && gc + 3 < PLD) {
                ushort4 u = *(const ushort4*)(A + (long)gk * PLD + gc);
                v = make_float4(h2f(u.x), h2f(u.y), h2f(u.z), h2f(u.w));
            }
            As[rr][c4 + 0] = v.x; As[rr][c4 + 1] = v.y; As[rr][c4 + 2] = v.z; As[rr][c4 + 3] = v.w;
        }
        {
            int r = t >> 4, c4 = (t & 15) << 2;
            int gk = kt + r;
            float4 v = make_float4(0.f, 0.f, 0.f, 0.f);
            if (gk < NTOK) {
                ushort4 u = *(const ushort4*)(B + (long)gk * D + c4);
                v = make_float4(h2f(u.x), h2f(u.y), h2f(u.z), h2f(u.w));
            }
            Bs[r][c4 + 0] = v.x; Bs[r][c4 + 1] = v.y; Bs[r][c4 + 2] = v.z; Bs[r][c4 + 3] = v.w;
        }
        __syncthreads();
#pragma unroll
        for (int kk = 0; kk < 16; kk++) {
            float av[4], bv[4];
#pragma unroll
            for (int i = 0; i < 4; i++) av[i] = As[kk][ty * 4 + i];
#pragma unroll
            for (int j = 0; j < 4; j++) bv[j] = Bs[kk][tx * 4 + j];
#pragma unroll
            for (int i = 0; i < 4; i++)
#pragma unroll
                for (int j = 0; j < 4; j++) acc[i][j] += av[i] * bv[j];
        }
        __syncthreads();
    }
#pragma unroll
    for (int i = 0; i < 4; i++) {
        int gr = row0 + ty * 4 + i;
        if (gr >= NTOK) continue;
#pragma unroll
        for (int j = 0; j < 4; j++) {
            int gc = tx * 4 + j;
            long idx = ((long)(b * NTOK + gr)) * D + h * HD + gc;
            G[idx] = f2h(acc[i][j]);
        }
    }
}

// ================= setup pieces =================

__global__ __launch_bounds__(256) void patchify_kernel(const float* __restrict__ x, u16* __restrict__ tok) {
    int idx = blockIdx.x * 256 + threadIdx.x;
    const int total = NB * NPATCH * D;
    if (idx >= total) return;
    int d = idx % D;
    int p = (idx / D) % NPATCH;
    int b = idx / (D * NPATCH);
    int c = d >> 8;
    int pi = (d >> 4) & 15;
    int pj = d & 15;
    int hp = p / 14, wp = p % 14;
    int row = hp * 16 + pi, col = wp * 16 + pj;
    tok[idx] = f2h(x[(((long)b * 3 + c) * 224 + row) * 224 + col]);
}

__global__ __launch_bounds__(256) void cls_pos_kernel(float* __restrict__ h, const float* __restrict__ cls,
                                                      const float* __restrict__ pos) {
    int idx = blockIdx.x * 256 + threadIdx.x;
    const int total = NB * NTOK * D;
    if (idx >= total) return;
    int d = idx % D;
    int n = (idx / D) % NTOK;
    float v = pos[n * D + d];
    if (n == 0) h[idx] = cls[d] + v;
    else        h[idx] = h[idx] + v;
}

__global__ __launch_bounds__(256) void wcat_kernel(const float* __restrict__ w, float* __restrict__ Wm) {
    int idx = blockIdx.x * 256 + threadIdx.x;
    const int total = NH * D * HD;
    if (idx >= total) return;
    int k = idx & 63;
    int d = (idx >> 6) % D;
    int hh = idx / (D * HD);
    Wm[d * D + hh * HD + k] = w[idx];
}

// ---------------- COALESCED tiled transpose prep: dst[c][r] = f2h(src[r][c]) ----------------
__global__ __launch_bounds__(256) void prep_transpose_h(const float* __restrict__ src,
                                                        u16* __restrict__ dst, int R, int C) {
    __shared__ float tile[32][33];
    int c0 = blockIdx.x * 32, r0 = blockIdx.y * 32;
    int tx = threadIdx.x & 31, ty = threadIdx.x >> 5;
    for (int i = ty; i < 32; i += 8)
        tile[i][tx] = src[(long)(r0 + i) * C + c0 + tx];
    __syncthreads();
    for (int i = ty; i < 32; i += 8)
        dst[(long)(c0 + i) * R + r0 + tx] = f2h(tile[tx][i]);
}
__global__ __launch_bounds__(256) void prep_convert_h(const float* __restrict__ src,
                                                      u16* __restrict__ dst, int n) {
    int idx = blockIdx.x * 256 + threadIdx.x;
    if (idx >= n) return;
    dst[idx] = f2h(src[idx]);
}

extern "C" void kernel_launch(void* const* d_in, const int* in_sizes, int n_in,
                              void* d_out, int out_size, void* d_ws, size_t ws_size,
                              hipStream_t stream) {
    const float* x        = (const float*)d_in[0];
    const float* patch_w  = (const float*)d_in[1];
    const float* patch_b  = (const float*)d_in[2];
    const float* cls_tok  = (const float*)d_in[3];
    const float* pos_emb  = (const float*)d_in[4];
    const float* ln_gamma = (const float*)d_in[5];
    const float* ln_beta  = (const float*)d_in[6];
    const float* wq       = (const float*)d_in[7];
    const float* wk       = (const float*)d_in[8];
    const float* xi       = (const float*)d_in[9];
    const float* out_gamma= (const float*)d_in[10];
    const float* out_beta = (const float*)d_in[11];
    const float* out_w    = (const float*)d_in[12];
    const float* out_b    = (const float*)d_in[13];
    float* out = (float*)d_out;

    float* ws = (float*)d_ws;
    const long SZ = SZL;
    const long AR = (long)AROWS * D;
    float* h  = ws;
    u16* gh16    = (u16*)(ws + SZ);
    u16* Qh16    = gh16 + AR;
    u16* Kh16    = Qh16 + AR;
    u16* WmQTh16 = Kh16 + AR;
    u16* WmKTh16 = WmQTh16 + DD;
    u16* WmQh16  = WmKTh16 + DD;
    u16* WmKh16  = WmQh16 + DD;
    u16* xiTh16  = WmKh16 + DD;
    u16* xibh16  = xiTh16 + DH;
    u16* G1h16   = xibh16 + DH;
    u16* G2h16   = G1h16 + AR;
    u16* HH16    = G2h16 + AR;
    u16* owTh16  = HH16 + (long)AROWS * HOP;
    u16* pwTh16  = owTh16 + DD;
    // shared region (sequenced aliasing): part (6*SZ u16) | Pt (192*PBH u16) | tok16 (setup)
    char* R1c = (char*)(pwTh16 + DD);
    u16* Pt16   = (u16*)R1c;
    u16* part16 = (u16*)R1c;
    u16* tok16  = (u16*)R1c;
    float* WmQ  = (float*)(R1c + (size_t)6 * SZ * 2);   // setup-only f32 scratch
    float* WmK  = WmQ + DD;

    // ---- setup ----
    patchify_kernel<<<(NB * NPATCH * D + 255) / 256, 256, 0, stream>>>(x, tok16);
    wcat_kernel<<<(NH * D * HD + 255) / 256, 256, 0, stream>>>(wq, WmQ);
    wcat_kernel<<<(NH * D * HD + 255) / 256, 256, 0, stream>>>(wk, WmK);
    prep_transpose_h<<<dim3(24, 24), 256, 0, stream>>>(WmQ, WmQTh16, 768, 768);
    prep_transpose_h<<<dim3(24, 24), 256, 0, stream>>>(WmK, WmKTh16, 768, 768);
    prep_convert_h<<<(DD + 255) / 256, 256, 0, stream>>>(WmQ, WmQh16, DD);
    prep_convert_h<<<(DD + 255) / 256, 256, 0, stream>>>(WmK, WmKh16, DD);
    prep_transpose_h<<<dim3(96, 24), 256, 0, stream>>>(xi, xiTh16, 768, HOP);
    prep_convert_h<<<(DH + 255) / 256, 256, 0, stream>>>(xi, xibh16, DH);
    prep_transpose_h<<<dim3(24, 24), 256, 0, stream>>>(out_w, owTh16, 768, 768);
    prep_transpose_h<<<dim3(24, 24), 256, 0, stream>>>(patch_w, pwTh16, 768, 768);
    // patch embed via fp16 MFMA: h rows 1..196 per batch (f32 out + f32 bias)
    gemm_h16<<<dim3(6, 2, NB), 256, 0, stream>>>(
        tok16, pwTh16, h + D, patch_b,
        NPATCH, D, D, D, D, D, 0,
        (long)NPATCH * D, 0, (long)NTOK * D);
    cls_pos_kernel<<<(NB * NTOK * D + 255) / 256, 256, 0, stream>>>(h, cls_tok, pos_emb);

    for (int step = 0; step < TSTEPS; step++) {
        ln_fuse_kernel<<<NROWS, 256, 0, stream>>>(h, gh16, part16, ln_gamma, ln_beta,
                                                  0, step > 0 ? 1 : 0, 1);
        fused_proj<<<900, 256, 0, stream>>>(gh16, WmQTh16, WmKTh16, xiTh16, Qh16, Kh16, HH16);
        attn_p_kernel<<<dim3(192, 13), 256, 0, stream>>>(Qh16, Kh16, Pt16);
        attn_g_kernel<<<dim3(1, 4, 384), 256, 0, stream>>>(Pt16, Qh16, Kh16, G1h16, G2h16);
        gemm_h16_fused<<<900, 256, 0, stream>>>(
            G1h16, G2h16, HH16, WmQh16, WmKh16, xibh16, part16);
    }

    // ---- final: reduce + LN (compact) -> fp16, then out projection (fp16 MFMA) ----
    ln_fuse_kernel<<<NPROWS, 256, 0, stream>>>(h, gh16, part16, out_gamma, out_beta, 1, 1, 0);
    gemm_h16<<<dim3(6, 25, 1), 256, 0, stream>>>(
        gh16, owTh16, out, out_b, NPROWS, D, D, D, D, D, 0, 0, 0, 0);
}

// Round 19
// 1077.295 us; speedup vs baseline: 1.7148x; 1.0683x over previous
//
#include <hip/hip_runtime.h>

#define NB 16
#define NTOK 197
#define NPATCH 196
#define D 768
#define NH 12
#define HD 64
#define HOP 3072
#define TSTEPS 6
#define BETA_F 0.125f
#define PLD 208                 // Pt leading dim (fp16)
#define PROWS 208               // Pt padded rows (pad rows zeroed)
#define PBH (PROWS * PLD)       // 43264
#define NROWS (NB * NTOK)       // 3152
#define NPROWS (NB * NPATCH)    // 3136
#define AROWS 3200              // padded rows for MFMA A-side staging
#define DD (768 * 768)
#define DH (768 * 3072)
#define SZL ((long)NROWS * D)   // 2,420,736

typedef unsigned short u16;
typedef __attribute__((ext_vector_type(8))) _Float16 f16x8;
typedef __attribute__((ext_vector_type(4))) float f32x4;

#define FLAG_ACC 1
#define FLAG_RELU 2
#define FLAG_H16 4

__device__ __forceinline__ u16 f2h(float f) {
    union { _Float16 h; u16 u; } cv;
    cv.h = (_Float16)f;
    return cv.u;
}
__device__ __forceinline__ float h2f(u16 v) {
    union { _Float16 h; u16 u; } cv;
    cv.u = v;
    return (float)cv.h;
}

__device__ __forceinline__ void gld16(const void* g, void* l) {
    __builtin_amdgcn_global_load_lds((const __attribute__((address_space(1))) void*)g,
                                     (__attribute__((address_space(3))) void*)l, 16, 0, 0);
}

// bijective XCD swizzle for nwg=900 on 8 XCDs (m204): chunks 4x113 + 4x112.
__device__ __forceinline__ int xcd_swz900(int bid) {
    int xcd = bid & 7, k = bid >> 3;
    return (xcd < 4 ? xcd * 113 : 452 + (xcd - 4) * 112) + k;
}

// ---------------- single-fp16 MFMA GEMM (patch embed, out-projection) ----------------
__global__ __launch_bounds__(256) void gemm_h16(
    const u16* __restrict__ A, const u16* __restrict__ B,
    void* __restrict__ Cv, const float* __restrict__ bias,
    int M, int N, int K, int lda, int ldbt, int ldc, int flags,
    long sAz, long sBz, long sCz) {
    __shared__ __align__(16) u16 As[128 * 32];
    __shared__ __align__(16) u16 Bs[128 * 32];
    int zz = blockIdx.z;
    A += (long)zz * sAz;
    B += (long)zz * sBz;
    long czoff = (long)zz * sCz;
    int t = threadIdx.x;
    int w = t >> 6, lane = t & 63;
    int lr = lane & 15, lg = lane >> 4;
    int wr = w >> 1, wc = w & 1;
    long row0 = (long)blockIdx.y * 128, col0 = (long)blockIdx.x * 128;

    f32x4 acc[4][4];
#pragma unroll
    for (int i = 0; i < 4; i++)
#pragma unroll
        for (int j = 0; j < 4; j++) acc[i][j] = (f32x4){0.f, 0.f, 0.f, 0.f};

    int c0 = w * 64 + lane;
    int r0s = c0 >> 2, k0s = (((c0 & 3) ^ ((r0s >> 1) & 3)) << 3);
    int c1 = 256 + w * 64 + lane;
    int r1s = c1 >> 2, k1s = (((c1 & 3) ^ ((r1s >> 1) & 3)) << 3);

    for (int kt = 0; kt < K; kt += 32) {
        const u16* AB = A + row0 * lda + kt;
        const u16* BB = B + col0 * ldbt + kt;
        gld16(AB + (long)r0s * lda + k0s, (char*)As + (w * 64) * 16);
        gld16(AB + (long)r1s * lda + k1s, (char*)As + (256 + w * 64) * 16);
        gld16(BB + (long)r0s * ldbt + k0s, (char*)Bs + (w * 64) * 16);
        gld16(BB + (long)r1s * ldbt + k1s, (char*)Bs + (256 + w * 64) * 16);
        __syncthreads();
        f16x8 af[4], bf[4];
#pragma unroll
        for (int mi = 0; mi < 4; mi++) {
            int row = wr * 64 + mi * 16 + lr;
            af[mi] = *(const f16x8*)&As[row * 32 + ((lg ^ ((row >> 1) & 3)) << 3)];
        }
#pragma unroll
        for (int ni = 0; ni < 4; ni++) {
            int row = wc * 64 + ni * 16 + lr;
            bf[ni] = *(const f16x8*)&Bs[row * 32 + ((lg ^ ((row >> 1) & 3)) << 3)];
        }
#pragma unroll
        for (int mi = 0; mi < 4; mi++)
#pragma unroll
            for (int ni = 0; ni < 4; ni++)
                acc[mi][ni] = __builtin_amdgcn_mfma_f32_16x16x32_f16(af[mi], bf[ni], acc[mi][ni], 0, 0, 0);
        __syncthreads();
    }

    long mbase = row0 + wr * 64;
    long nbase = col0 + wc * 64;
#pragma unroll
    for (int mi = 0; mi < 4; mi++) {
#pragma unroll
        for (int r = 0; r < 4; r++) {
            long grow = mbase + mi * 16 + lg * 4 + r;
            if (grow >= M) continue;
#pragma unroll
            for (int ni = 0; ni < 4; ni++) {
                long gcol = nbase + ni * 16 + lr;
                float v = acc[mi][ni][r];
                if (bias) v += bias[gcol];
                if (flags & FLAG_RELU) v = fmaxf(v, 0.f);
                long idx = czoff + grow * ldc + gcol;
                if (flags & FLAG_ACC) ((float*)Cv)[idx] += v;
                else if (flags & FLAG_H16) ((u16*)Cv)[idx] = f2h(v);
                else ((float*)Cv)[idx] = v;
            }
        }
    }
}

// ---------------- fused projection: Q,K (fp16 out) + Hopfield-1 (fp16+relu); XCD-swizzled 1D grid 900 ----------------
__global__ __launch_bounds__(256) void fused_proj(
    const u16* __restrict__ A,
    const u16* __restrict__ WQT, const u16* __restrict__ WKT, const u16* __restrict__ XIT,
    u16* __restrict__ Qh, u16* __restrict__ Kh, u16* __restrict__ HH) {
    __shared__ __align__(16) u16 As[128 * 32];
    __shared__ __align__(16) u16 Bs[128 * 32];
    int lid = xcd_swz900(blockIdx.x);
    int cx = lid % 36, by = lid / 36;
    const u16* B; int ldc; long col0; int mode;
    if (cx < 6)       { B = WQT; ldc = 768;  col0 = (long)cx * 128;        mode = 0; }
    else if (cx < 12) { B = WKT; ldc = 768;  col0 = (long)(cx - 6) * 128;  mode = 1; }
    else              { B = XIT; ldc = 3072; col0 = (long)(cx - 12) * 128; mode = 2; }
    int t = threadIdx.x;
    int w = t >> 6, lane = t & 63;
    int lr = lane & 15, lg = lane >> 4;
    int wr = w >> 1, wc = w & 1;
    long row0 = (long)by * 128;

    f32x4 acc[4][4];
#pragma unroll
    for (int i = 0; i < 4; i++)
#pragma unroll
        for (int j = 0; j < 4; j++) acc[i][j] = (f32x4){0.f, 0.f, 0.f, 0.f};

    int c0 = w * 64 + lane;
    int r0s = c0 >> 2, k0s = (((c0 & 3) ^ ((r0s >> 1) & 3)) << 3);
    int c1 = 256 + w * 64 + lane;
    int r1s = c1 >> 2, k1s = (((c1 & 3) ^ ((r1s >> 1) & 3)) << 3);

    for (int kt = 0; kt < 768; kt += 32) {
        const u16* AB = A + row0 * 768 + kt;
        const u16* BB = B + col0 * 768 + kt;
        gld16(AB + (long)r0s * 768 + k0s, (char*)As + (w * 64) * 16);
        gld16(AB + (long)r1s * 768 + k1s, (char*)As + (256 + w * 64) * 16);
        gld16(BB + (long)r0s * 768 + k0s, (char*)Bs + (w * 64) * 16);
        gld16(BB + (long)r1s * 768 + k1s, (char*)Bs + (256 + w * 64) * 16);
        __syncthreads();
        f16x8 af[4], bf[4];
#pragma unroll
        for (int mi = 0; mi < 4; mi++) {
            int row = wr * 64 + mi * 16 + lr;
            af[mi] = *(const f16x8*)&As[row * 32 + ((lg ^ ((row >> 1) & 3)) << 3)];
        }
#pragma unroll
        for (int ni = 0; ni < 4; ni++) {
            int row = wc * 64 + ni * 16 + lr;
            bf[ni] = *(const f16x8*)&Bs[row * 32 + ((lg ^ ((row >> 1) & 3)) << 3)];
        }
#pragma unroll
        for (int mi = 0; mi < 4; mi++)
#pragma unroll
            for (int ni = 0; ni < 4; ni++)
                acc[mi][ni] = __builtin_amdgcn_mfma_f32_16x16x32_f16(af[mi], bf[ni], acc[mi][ni], 0, 0, 0);
        __syncthreads();
    }

    long mbase = row0 + wr * 64;
    long nbase = col0 + wc * 64;
#pragma unroll
    for (int mi = 0; mi < 4; mi++) {
#pragma unroll
        for (int r = 0; r < 4; r++) {
            long grow = mbase + mi * 16 + lg * 4 + r;
            if (grow >= NROWS) continue;
#pragma unroll
            for (int ni = 0; ni < 4; ni++) {
                long gcol = nbase + ni * 16 + lr;
                float v = acc[mi][ni][r];
                long idx = grow * ldc + gcol;
                if (mode == 0)      Qh[idx] = f2h(v);
                else if (mode == 1) Kh[idx] = f2h(v);
                else                HH[idx] = f2h(fmaxf(v, 0.f));
            }
        }
    }
}

// ---------------- fused accumulate GEMM: 6 split-K partials -> fp16 slabs; XCD-swizzled 1D grid 900 ----------------
__global__ __launch_bounds__(256) void gemm_h16_fused(
    const u16* __restrict__ G1, const u16* __restrict__ G2, const u16* __restrict__ HH,
    const u16* __restrict__ WQ, const u16* __restrict__ WK, const u16* __restrict__ XB,
    u16* __restrict__ part) {
    __shared__ __align__(16) u16 As[128 * 32];
    __shared__ __align__(16) u16 Bs[128 * 32];
    int lid = xcd_swz900(blockIdx.x);
    int bx = lid % 6, by = (lid / 6) % 25, zz = lid / 150;
    const u16* A; const u16* B; int lda; int K0;
    if (zz == 0)      { A = G1; B = WQ; lda = 768;  K0 = 0; }
    else if (zz == 1) { A = G2; B = WK; lda = 768;  K0 = 0; }
    else              { A = HH; B = XB; lda = 3072; K0 = (zz - 2) * 768; }
    u16* C = part + (long)zz * SZL;

    int t = threadIdx.x;
    int w = t >> 6, lane = t & 63;
    int lr = lane & 15, lg = lane >> 4;
    int wr = w >> 1, wc = w & 1;
    long row0 = (long)by * 128, col0 = (long)bx * 128;

    f32x4 acc[4][4];
#pragma unroll
    for (int i = 0; i < 4; i++)
#pragma unroll
        for (int j = 0; j < 4; j++) acc[i][j] = (f32x4){0.f, 0.f, 0.f, 0.f};

    int c0 = w * 64 + lane;
    int r0s = c0 >> 2, k0s = (((c0 & 3) ^ ((r0s >> 1) & 3)) << 3);
    int c1 = 256 + w * 64 + lane;
    int r1s = c1 >> 2, k1s = (((c1 & 3) ^ ((r1s >> 1) & 3)) << 3);

    for (int kt = K0; kt < K0 + 768; kt += 32) {
        const u16* AB = A + row0 * lda + kt;
        const u16* BB = B + col0 * (long)lda + kt;
        gld16(AB + (long)r0s * lda + k0s, (char*)As + (w * 64) * 16);
        gld16(AB + (long)r1s * lda + k1s, (char*)As + (256 + w * 64) * 16);
        gld16(BB + (long)r0s * lda + k0s, (char*)Bs + (w * 64) * 16);
        gld16(BB + (long)r1s * lda + k1s, (char*)Bs + (256 + w * 64) * 16);
        __syncthreads();
        f16x8 af[4], bf[4];
#pragma unroll
        for (int mi = 0; mi < 4; mi++) {
            int row = wr * 64 + mi * 16 + lr;
            af[mi] = *(const f16x8*)&As[row * 32 + ((lg ^ ((row >> 1) & 3)) << 3)];
        }
#pragma unroll
        for (int ni = 0; ni < 4; ni++) {
            int row = wc * 64 + ni * 16 + lr;
            bf[ni] = *(const f16x8*)&Bs[row * 32 + ((lg ^ ((row >> 1) & 3)) << 3)];
        }
#pragma unroll
        for (int mi = 0; mi < 4; mi++)
#pragma unroll
            for (int ni = 0; ni < 4; ni++)
                acc[mi][ni] = __builtin_amdgcn_mfma_f32_16x16x32_f16(af[mi], bf[ni], acc[mi][ni], 0, 0, 0);
        __syncthreads();
    }

    long mbase = row0 + wr * 64;
    long nbase = col0 + wc * 64;
#pragma unroll
    for (int mi = 0; mi < 4; mi++) {
#pragma unroll
        for (int r = 0; r < 4; r++) {
            long grow = mbase + mi * 16 + lg * 4 + r;
            if (grow >= NROWS) continue;
#pragma unroll
            for (int ni = 0; ni < 4; ni++) {
                long gcol = nbase + ni * 16 + lr;
                C[grow * D + gcol] = f2h(acc[mi][ni][r]);
            }
        }
    }
}

// ---------------- fused reduce + layernorm: h (+= 6 fp16 slabs) -> LN -> fp16 ----------------
__global__ __launch_bounds__(256) void ln_fuse_kernel(
    float* __restrict__ X, u16* __restrict__ Yh16, const u16* __restrict__ part,
    const float* __restrict__ gamma, const float* __restrict__ beta,
    int compact, int doReduce, int writeBack) {
    int r = blockIdx.x;
    long xrow = compact ? ((long)(r / NPATCH) * NTOK + 1 + (r % NPATCH)) : (long)r;
    float* x = X + xrow * D;
    int t = threadIdx.x;
    float v[3];
    float s = 0.f, ss = 0.f;
#pragma unroll
    for (int i = 0; i < 3; i++) {
        int c = t + 256 * i;
        float val = x[c];
        if (doReduce) {
            long off = xrow * D + c;
            float p01 = h2f(part[off]) + h2f(part[SZL + off]);
            float p23 = h2f(part[2 * SZL + off]) + h2f(part[3 * SZL + off]);
            float p45 = h2f(part[4 * SZL + off]) + h2f(part[5 * SZL + off]);
            val += (p01 + p23) + p45;
            if (writeBack) x[c] = val;
        }
        v[i] = val;
        s += val;
        ss += val * val;
    }
    __shared__ float red[8];
    for (int off = 32; off; off >>= 1) {
        s += __shfl_down(s, off, 64);
        ss += __shfl_down(ss, off, 64);
    }
    int wid = t >> 6, lane = t & 63;
    if (lane == 0) { red[wid] = s; red[4 + wid] = ss; }
    __syncthreads();
    s = red[0] + red[1] + red[2] + red[3];
    ss = red[4] + red[5] + red[6] + red[7];
    float mu = s * (1.f / 768.f);
    float var = ss * (1.f / 768.f) - mu * mu;
    float inv = rsqrtf(var + 1e-5f);
#pragma unroll
    for (int i = 0; i < 3; i++) {
        int c = t + 256 * i;
        float yv = gamma[c] * (v[i] - mu) * inv + beta[c];
        Yh16[(long)r * D + c] = f2h(yv);
    }
}

// ---------------- parallel attention softmax (fp16 Q/K in, fp16 Pt out; grid 192x13) ----------------
// Pads: rows 197..207 AND cols 197..207 written as ZERO every step (MFMA downstream requires).
__global__ __launch_bounds__(256) void attn_p_kernel(const u16* __restrict__ Q, const u16* __restrict__ K,
                                                     u16* __restrict__ Pt) {
    __shared__ __align__(16) u16 Ks[NTOK][72];
    int bh = blockIdx.x, mt = blockIdx.y;
    int b = bh / NH, h = bh % NH;
    int t = threadIdx.x;
    const u16* Kb = K + (long)b * NTOK * D + h * HD;
    for (int i = t; i < NTOK * 8; i += 256) {
        int n = i >> 3, c8 = (i & 7) << 3;
        *(uint4*)&Ks[n][c8] = *(const uint4*)(Kb + (long)n * D + c8);
    }
    __syncthreads();
    int ql = t >> 4, l16 = t & 15;
    int m = mt * 16 + ql;
    int mr = m < NTOK ? m : NTOK - 1;
    const u16* Qrow = Q + (long)(b * NTOK + mr) * D + h * HD;
    float q[64];
#pragma unroll
    for (int k = 0; k < 64; k += 8) {
        f16x8 v = *(const f16x8*)(Qrow + k);
#pragma unroll
        for (int j = 0; j < 8; j++) q[k + j] = (float)v[j];
    }
    float s[13];
    float mx = -1e30f;
#pragma unroll
    for (int i = 0; i < 13; i++) {
        int n = i * 16 + l16;
        const u16* kr = Ks[n < NTOK ? n : 0];
        float a0 = 0.f, a1 = 0.f, a2 = 0.f, a3 = 0.f;
#pragma unroll
        for (int k = 0; k < 64; k += 8) {
            f16x8 kv = *(const f16x8*)&kr[k];
            a0 += (float)kv[0] * q[k]     + (float)kv[4] * q[k + 4];
            a1 += (float)kv[1] * q[k + 1] + (float)kv[5] * q[k + 5];
            a2 += (float)kv[2] * q[k + 2] + (float)kv[6] * q[k + 6];
            a3 += (float)kv[3] * q[k + 3] + (float)kv[7] * q[k + 7];
        }
        float sv = ((a0 + a1) + (a2 + a3)) * BETA_F;
        s[i] = (n < NTOK) ? sv : -1e30f;
        mx = fmaxf(mx, s[i]);
    }
    mx = fmaxf(mx, __shfl_xor(mx, 1, 64));
    mx = fmaxf(mx, __shfl_xor(mx, 2, 64));
    mx = fmaxf(mx, __shfl_xor(mx, 4, 64));
    mx = fmaxf(mx, __shfl_xor(mx, 8, 64));
    float ssum = 0.f;
#pragma unroll
    for (int i = 0; i < 13; i++) {
        float e = (s[i] > -1e29f) ? __expf(s[i] - mx) : 0.f;
        s[i] = e;
        ssum += e;
    }
    ssum += __shfl_xor(ssum, 1, 64);
    ssum += __shfl_xor(ssum, 2, 64);
    ssum += __shfl_xor(ssum, 4, 64);
    ssum += __shfl_xor(ssum, 8, 64);
    float inv = 1.f / ssum;
    u16* PtB = Pt + (long)bh * PBH;
    if (m < NTOK) {
#pragma unroll
        for (int i = 0; i < 13; i++) {
            int n = i * 16 + l16;
            PtB[(long)m * PLD + n] = (n < NTOK) ? f2h(s[i] * inv) : (u16)0;
        }
    } else {
        // zero pad rows 197..207 entirely
#pragma unroll
        for (int i = 0; i < 13; i++) {
            int n = i * 16 + l16;
            PtB[(long)m * PLD + n] = 0;
        }
    }
}

// ---------------- attention grads via MFMA: G1 (which=0) + G2 (which=1) ----------------
// C[208x64] = A x B^T with K padded to 224 (zeros on both operands).
// which=0: A[r][k] = Pt[row0+r][k] (k = key token n); B[c][k] = K[k][c]
// which=1: A[r][k] = Pt[k][row0+r] (k = query token m); B[c][k] = Q[k][c]
__global__ __launch_bounds__(256) void attn_g_mfma(
    const u16* __restrict__ Pt, const u16* __restrict__ Qh, const u16* __restrict__ Kh,
    u16* __restrict__ G1, u16* __restrict__ G2) {
    __shared__ __align__(16) u16 Asm[64][224];
    __shared__ __align__(16) u16 Bsm[64][224];
    int z = blockIdx.z;
    int which = z / 192, bh = z - which * 192;
    int b = bh / NH, h = bh % NH;
    int row0 = blockIdx.x * 64;
    const u16* P = Pt + (long)bh * PBH;
    const u16* B = (which ? Qh : Kh) + ((long)b * NTOK) * D + h * HD;
    u16* G = which ? G2 : G1;
    int t = threadIdx.x;

    // ---- stage A ----
    if (which == 0) {
        for (int idx = t; idx < 64 * 28; idx += 256) {
            int r = idx / 28, c8 = (idx % 28) * 8;
            uint4 v = make_uint4(0, 0, 0, 0);
            if (row0 + r < PROWS && c8 < PLD)
                v = *(const uint4*)(P + (long)(row0 + r) * PLD + c8);
            *(uint4*)&Asm[r][c8] = v;
        }
    } else {
        for (int idx = t; idx < 224 * 8; idx += 256) {
            int m = idx / 8, j8 = (idx % 8) * 8;
            u16 vals[8];
            if (m < PROWS && row0 + j8 < PLD) {
                *(uint4*)vals = *(const uint4*)(P + (long)m * PLD + row0 + j8);
            } else {
#pragma unroll
                for (int j = 0; j < 8; j++) vals[j] = 0;
            }
#pragma unroll
            for (int j = 0; j < 8; j++) Asm[j8 + j][m] = vals[j];
        }
    }
    // ---- stage B (transposed): Bsm[c][k] = B[k*D + c]; k >= 208 -> 0 ----
    for (int idx = t; idx < 224 * 8; idx += 256) {
        int n = idx / 8, c8 = (idx % 8) * 8;
        u16 vals[8];
        if (n < PROWS) {
            *(uint4*)vals = *(const uint4*)(B + (long)n * D + c8);
        } else {
#pragma unroll
            for (int j = 0; j < 8; j++) vals[j] = 0;
        }
#pragma unroll
        for (int j = 0; j < 8; j++) Bsm[c8 + j][n] = vals[j];
    }
    __syncthreads();

    int w = t >> 6, lane = t & 63;
    int lr = lane & 15, lg = lane >> 4;
    f32x4 acc[4];
#pragma unroll
    for (int i = 0; i < 4; i++) acc[i] = (f32x4){0.f, 0.f, 0.f, 0.f};
#pragma unroll
    for (int kt = 0; kt < 224; kt += 32) {
        f16x8 a = *(const f16x8*)&Asm[w * 16 + lr][kt + lg * 8];
#pragma unroll
        for (int ni = 0; ni < 4; ni++) {
            f16x8 bfr = *(const f16x8*)&Bsm[ni * 16 + lr][kt + lg * 8];
            acc[ni] = __builtin_amdgcn_mfma_f32_16x16x32_f16(a, bfr, acc[ni], 0, 0, 0);
        }
    }

#pragma unroll
    for (int ni = 0; ni < 4; ni++) {
#pragma unroll
        for (int r = 0; r < 4; r++) {
            int m = row0 + w * 16 + lg * 4 + r;
            if (m < NTOK) {
                int c = ni * 16 + lr;
                G[((long)(b * NTOK + m)) * D + h * HD + c] = f2h(acc[ni][r]);
            }
        }
    }
}

// ================= setup pieces =================

__global__ __launch_bounds__(256) void patchify_kernel(const float* __restrict__ x, u16* __restrict__ tok) {
    int idx = blockIdx.x * 256 + threadIdx.x;
    const int total = NB * NPATCH * D;
    if (idx >= total) return;
    int d = idx % D;
    int p = (idx / D) % NPATCH;
    int b = idx / (D * NPATCH);
    int c = d >> 8;
    int pi = (d >> 4) & 15;
    int pj = d & 15;
    int hp = p / 14, wp = p % 14;
    int row = hp * 16 + pi, col = wp * 16 + pj;
    tok[idx] = f2h(x[(((long)b * 3 + c) * 224 + row) * 224 + col]);
}

__global__ __launch_bounds__(256) void cls_pos_kernel(float* __restrict__ h, const float* __restrict__ cls,
                                                      const float* __restrict__ pos) {
    int idx = blockIdx.x * 256 + threadIdx.x;
    const int total = NB * NTOK * D;
    if (idx >= total) return;
    int d = idx % D;
    int n = (idx / D) % NTOK;
    float v = pos[n * D + d];
    if (n == 0) h[idx] = cls[d] + v;
    else        h[idx] = h[idx] + v;
}

__global__ __launch_bounds__(256) void wcat_kernel(const float* __restrict__ w, float* __restrict__ Wm) {
    int idx = blockIdx.x * 256 + threadIdx.x;
    const int total = NH * D * HD;
    if (idx >= total) return;
    int k = idx & 63;
    int d = (idx >> 6) % D;
    int hh = idx / (D * HD);
    Wm[d * D + hh * HD + k] = w[idx];
}

// ---------------- COALESCED tiled transpose prep: dst[c][r] = f2h(src[r][c]) ----------------
__global__ __launch_bounds__(256) void prep_transpose_h(const float* __restrict__ src,
                                                        u16* __restrict__ dst, int R, int C) {
    __shared__ float tile[32][33];
    int c0 = blockIdx.x * 32, r0 = blockIdx.y * 32;
    int tx = threadIdx.x & 31, ty = threadIdx.x >> 5;
    for (int i = ty; i < 32; i += 8)
        tile[i][tx] = src[(long)(r0 + i) * C + c0 + tx];
    __syncthreads();
    for (int i = ty; i < 32; i += 8)
        dst[(long)(c0 + i) * R + r0 + tx] = f2h(tile[tx][i]);
}
__global__ __launch_bounds__(256) void prep_convert_h(const float* __restrict__ src,
                                                      u16* __restrict__ dst, int n) {
    int idx = blockIdx.x * 256 + threadIdx.x;
    if (idx >= n) return;
    dst[idx] = f2h(src[idx]);
}

extern "C" void kernel_launch(void* const* d_in, const int* in_sizes, int n_in,
                              void* d_out, int out_size, void* d_ws, size_t ws_size,
                              hipStream_t stream) {
    const float* x        = (const float*)d_in[0];
    const float* patch_w  = (const float*)d_in[1];
    const float* patch_b  = (const float*)d_in[2];
    const float* cls_tok  = (const float*)d_in[3];
    const float* pos_emb  = (const float*)d_in[4];
    const float* ln_gamma = (const float*)d_in[5];
    const float* ln_beta  = (const float*)d_in[6];
    const float* wq       = (const float*)d_in[7];
    const float* wk       = (const float*)d_in[8];
    const float* xi       = (const float*)d_in[9];
    const float* out_gamma= (const float*)d_in[10];
    const float* out_beta = (const float*)d_in[11];
    const float* out_w    = (const float*)d_in[12];
    const float* out_b    = (const float*)d_in[13];
    float* out = (float*)d_out;

    float* ws = (float*)d_ws;
    const long SZ = SZL;
    const long AR = (long)AROWS * D;
    float* h  = ws;
    u16* gh16    = (u16*)(ws + SZ);
    u16* Qh16    = gh16 + AR;
    u16* Kh16    = Qh16 + AR;
    u16* WmQTh16 = Kh16 + AR;
    u16* WmKTh16 = WmQTh16 + DD;
    u16* WmQh16  = WmKTh16 + DD;
    u16* WmKh16  = WmQh16 + DD;
    u16* xiTh16  = WmKh16 + DD;
    u16* xibh16  = xiTh16 + DH;
    u16* G1h16   = xibh16 + DH;
    u16* G2h16   = G1h16 + AR;
    u16* HH16    = G2h16 + AR;
    u16* owTh16  = HH16 + (long)AROWS * HOP;
    u16* pwTh16  = owTh16 + DD;
    // shared region (sequenced aliasing): part (6*SZ u16) | Pt (192*PBH u16) | tok16 (setup)
    char* R1c = (char*)(pwTh16 + DD);
    u16* Pt16   = (u16*)R1c;
    u16* part16 = (u16*)R1c;
    u16* tok16  = (u16*)R1c;
    float* WmQ  = (float*)(R1c + (size_t)6 * SZ * 2);   // setup-only f32 scratch
    float* WmK  = WmQ + DD;

    // ---- setup ----
    patchify_kernel<<<(NB * NPATCH * D + 255) / 256, 256, 0, stream>>>(x, tok16);
    wcat_kernel<<<(NH * D * HD + 255) / 256, 256, 0, stream>>>(wq, WmQ);
    wcat_kernel<<<(NH * D * HD + 255) / 256, 256, 0, stream>>>(wk, WmK);
    prep_transpose_h<<<dim3(24, 24), 256, 0, stream>>>(WmQ, WmQTh16, 768, 768);
    prep_transpose_h<<<dim3(24, 24), 256, 0, stream>>>(WmK, WmKTh16, 768, 768);
    prep_convert_h<<<(DD + 255) / 256, 256, 0, stream>>>(WmQ, WmQh16, DD);
    prep_convert_h<<<(DD + 255) / 256, 256, 0, stream>>>(WmK, WmKh16, DD);
    prep_transpose_h<<<dim3(96, 24), 256, 0, stream>>>(xi, xiTh16, 768, HOP);
    prep_convert_h<<<(DH + 255) / 256, 256, 0, stream>>>(xi, xibh16, DH);
    prep_transpose_h<<<dim3(24, 24), 256, 0, stream>>>(out_w, owTh16, 768, 768);
    prep_transpose_h<<<dim3(24, 24), 256, 0, stream>>>(patch_w, pwTh16, 768, 768);
    // patch embed via fp16 MFMA: h rows 1..196 per batch (f32 out + f32 bias)
    gemm_h16<<<dim3(6, 2, NB), 256, 0, stream>>>(
        tok16, pwTh16, h + D, patch_b,
        NPATCH, D, D, D, D, D, 0,
        (long)NPATCH * D, 0, (long)NTOK * D);
    cls_pos_kernel<<<(NB * NTOK * D + 255) / 256, 256, 0, stream>>>(h, cls_tok, pos_emb);

    for (int step = 0; step < TSTEPS; step++) {
        ln_fuse_kernel<<<NROWS, 256, 0, stream>>>(h, gh16, part16, ln_gamma, ln_beta,
                                                  0, step > 0 ? 1 : 0, 1);
        fused_proj<<<900, 256, 0, stream>>>(gh16, WmQTh16, WmKTh16, xiTh16, Qh16, Kh16, HH16);
        attn_p_kernel<<<dim3(192, 13), 256, 0, stream>>>(Qh16, Kh16, Pt16);
        attn_g_mfma<<<dim3(4, 1, 384), 256, 0, stream>>>(Pt16, Qh16, Kh16, G1h16, G2h16);
        gemm_h16_fused<<<900, 256, 0, stream>>>(
            G1h16, G2h16, HH16, WmQh16, WmKh16, xibh16, part16);
    }

    // ---- final: reduce + LN (compact) -> fp16, then out projection (fp16 MFMA) ----
    ln_fuse_kernel<<<NPROWS, 256, 0, stream>>>(h, gh16, part16, out_gamma, out_beta, 1, 1, 0);
    gemm_h16<<<dim3(6, 25, 1), 256, 0, stream>>>(
        gh16, owTh16, out, out_b, NPROWS, D, D, D, D, D, 0, 0, 0, 0);
}

// Round 20
// 975.253 us; speedup vs baseline: 1.8942x; 1.1046x over previous
//
#include <hip/hip_runtime.h>

#define NB 16
#define NTOK 197
#define NPATCH 196
#define D 768
#define NH 12
#define HD 64
#define HOP 3072
#define TSTEPS 6
#define BETA_F 0.125f
#define PLD 208                 // Pt leading dim (fp16)
#define PROWS 208               // Pt padded rows (pad rows zeroed)
#define PBH (PROWS * PLD)       // 43264
#define NROWS (NB * NTOK)       // 3152
#define NPROWS (NB * NPATCH)    // 3136
#define AROWS 3200              // padded rows for MFMA A-side staging
#define DD (768 * 768)
#define DH (768 * 3072)
#define SZL ((long)NROWS * D)   // 2,420,736

typedef unsigned short u16;
typedef __attribute__((ext_vector_type(8))) _Float16 f16x8;
typedef __attribute__((ext_vector_type(2))) _Float16 f16x2;
typedef __attribute__((ext_vector_type(4))) float f32x4;

#define FLAG_ACC 1
#define FLAG_RELU 2
#define FLAG_H16 4

__device__ __forceinline__ u16 f2h(float f) {
    union { _Float16 h; u16 u; } cv;
    cv.h = (_Float16)f;
    return cv.u;
}
__device__ __forceinline__ float h2f(u16 v) {
    union { _Float16 h; u16 u; } cv;
    cv.u = v;
    return (float)cv.h;
}

__device__ __forceinline__ void gld16(const void* g, void* l) {
    __builtin_amdgcn_global_load_lds((const __attribute__((address_space(1))) void*)g,
                                     (__attribute__((address_space(3))) void*)l, 16, 0, 0);
}

// bijective XCD swizzle for nwg=900 on 8 XCDs (m204): chunks 4x113 + 4x112.
__device__ __forceinline__ int xcd_swz900(int bid) {
    int xcd = bid & 7, k = bid >> 3;
    return (xcd < 4 ? xcd * 113 : 452 + (xcd - 4) * 112) + k;
}

// ---------------- single-fp16 MFMA GEMM (patch embed, out-projection) ----------------
__global__ __launch_bounds__(256) void gemm_h16(
    const u16* __restrict__ A, const u16* __restrict__ B,
    void* __restrict__ Cv, const float* __restrict__ bias,
    int M, int N, int K, int lda, int ldbt, int ldc, int flags,
    long sAz, long sBz, long sCz) {
    __shared__ __align__(16) u16 As[128 * 32];
    __shared__ __align__(16) u16 Bs[128 * 32];
    int zz = blockIdx.z;
    A += (long)zz * sAz;
    B += (long)zz * sBz;
    long czoff = (long)zz * sCz;
    int t = threadIdx.x;
    int w = t >> 6, lane = t & 63;
    int lr = lane & 15, lg = lane >> 4;
    int wr = w >> 1, wc = w & 1;
    long row0 = (long)blockIdx.y * 128, col0 = (long)blockIdx.x * 128;

    f32x4 acc[4][4];
#pragma unroll
    for (int i = 0; i < 4; i++)
#pragma unroll
        for (int j = 0; j < 4; j++) acc[i][j] = (f32x4){0.f, 0.f, 0.f, 0.f};

    int c0 = w * 64 + lane;
    int r0s = c0 >> 2, k0s = (((c0 & 3) ^ ((r0s >> 1) & 3)) << 3);
    int c1 = 256 + w * 64 + lane;
    int r1s = c1 >> 2, k1s = (((c1 & 3) ^ ((r1s >> 1) & 3)) << 3);

    for (int kt = 0; kt < K; kt += 32) {
        const u16* AB = A + row0 * lda + kt;
        const u16* BB = B + col0 * ldbt + kt;
        gld16(AB + (long)r0s * lda + k0s, (char*)As + (w * 64) * 16);
        gld16(AB + (long)r1s * lda + k1s, (char*)As + (256 + w * 64) * 16);
        gld16(BB + (long)r0s * ldbt + k0s, (char*)Bs + (w * 64) * 16);
        gld16(BB + (long)r1s * ldbt + k1s, (char*)Bs + (256 + w * 64) * 16);
        __syncthreads();
        f16x8 af[4], bf[4];
#pragma unroll
        for (int mi = 0; mi < 4; mi++) {
            int row = wr * 64 + mi * 16 + lr;
            af[mi] = *(const f16x8*)&As[row * 32 + ((lg ^ ((row >> 1) & 3)) << 3)];
        }
#pragma unroll
        for (int ni = 0; ni < 4; ni++) {
            int row = wc * 64 + ni * 16 + lr;
            bf[ni] = *(const f16x8*)&Bs[row * 32 + ((lg ^ ((row >> 1) & 3)) << 3)];
        }
#pragma unroll
        for (int mi = 0; mi < 4; mi++)
#pragma unroll
            for (int ni = 0; ni < 4; ni++)
                acc[mi][ni] = __builtin_amdgcn_mfma_f32_16x16x32_f16(af[mi], bf[ni], acc[mi][ni], 0, 0, 0);
        __syncthreads();
    }

    long mbase = row0 + wr * 64;
    long nbase = col0 + wc * 64;
#pragma unroll
    for (int mi = 0; mi < 4; mi++) {
#pragma unroll
        for (int r = 0; r < 4; r++) {
            long grow = mbase + mi * 16 + lg * 4 + r;
            if (grow >= M) continue;
#pragma unroll
            for (int ni = 0; ni < 4; ni++) {
                long gcol = nbase + ni * 16 + lr;
                float v = acc[mi][ni][r];
                if (bias) v += bias[gcol];
                if (flags & FLAG_RELU) v = fmaxf(v, 0.f);
                long idx = czoff + grow * ldc + gcol;
                if (flags & FLAG_ACC) ((float*)Cv)[idx] += v;
                else if (flags & FLAG_H16) ((u16*)Cv)[idx] = f2h(v);
                else ((float*)Cv)[idx] = v;
            }
        }
    }
}

// ---------------- fused projection: Q,K (fp16 out) + Hopfield-1 (fp16+relu); XCD-swizzled 1D grid 900 ----------------
__global__ __launch_bounds__(256) void fused_proj(
    const u16* __restrict__ A,
    const u16* __restrict__ WQT, const u16* __restrict__ WKT, const u16* __restrict__ XIT,
    u16* __restrict__ Qh, u16* __restrict__ Kh, u16* __restrict__ HH) {
    __shared__ __align__(16) u16 As[128 * 32];
    __shared__ __align__(16) u16 Bs[128 * 32];
    int lid = xcd_swz900(blockIdx.x);
    int cx = lid % 36, by = lid / 36;
    const u16* B; int ldc; long col0; int mode;
    if (cx < 6)       { B = WQT; ldc = 768;  col0 = (long)cx * 128;        mode = 0; }
    else if (cx < 12) { B = WKT; ldc = 768;  col0 = (long)(cx - 6) * 128;  mode = 1; }
    else              { B = XIT; ldc = 3072; col0 = (long)(cx - 12) * 128; mode = 2; }
    int t = threadIdx.x;
    int w = t >> 6, lane = t & 63;
    int lr = lane & 15, lg = lane >> 4;
    int wr = w >> 1, wc = w & 1;
    long row0 = (long)by * 128;

    f32x4 acc[4][4];
#pragma unroll
    for (int i = 0; i < 4; i++)
#pragma unroll
        for (int j = 0; j < 4; j++) acc[i][j] = (f32x4){0.f, 0.f, 0.f, 0.f};

    int c0 = w * 64 + lane;
    int r0s = c0 >> 2, k0s = (((c0 & 3) ^ ((r0s >> 1) & 3)) << 3);
    int c1 = 256 + w * 64 + lane;
    int r1s = c1 >> 2, k1s = (((c1 & 3) ^ ((r1s >> 1) & 3)) << 3);

    for (int kt = 0; kt < 768; kt += 32) {
        const u16* AB = A + row0 * 768 + kt;
        const u16* BB = B + col0 * 768 + kt;
        gld16(AB + (long)r0s * 768 + k0s, (char*)As + (w * 64) * 16);
        gld16(AB + (long)r1s * 768 + k1s, (char*)As + (256 + w * 64) * 16);
        gld16(BB + (long)r0s * 768 + k0s, (char*)Bs + (w * 64) * 16);
        gld16(BB + (long)r1s * 768 + k1s, (char*)Bs + (256 + w * 64) * 16);
        __syncthreads();
        f16x8 af[4], bf[4];
#pragma unroll
        for (int mi = 0; mi < 4; mi++) {
            int row = wr * 64 + mi * 16 + lr;
            af[mi] = *(const f16x8*)&As[row * 32 + ((lg ^ ((row >> 1) & 3)) << 3)];
        }
#pragma unroll
        for (int ni = 0; ni < 4; ni++) {
            int row = wc * 64 + ni * 16 + lr;
            bf[ni] = *(const f16x8*)&Bs[row * 32 + ((lg ^ ((row >> 1) & 3)) << 3)];
        }
#pragma unroll
        for (int mi = 0; mi < 4; mi++)
#pragma unroll
            for (int ni = 0; ni < 4; ni++)
                acc[mi][ni] = __builtin_amdgcn_mfma_f32_16x16x32_f16(af[mi], bf[ni], acc[mi][ni], 0, 0, 0);
        __syncthreads();
    }

    long mbase = row0 + wr * 64;
    long nbase = col0 + wc * 64;
#pragma unroll
    for (int mi = 0; mi < 4; mi++) {
#pragma unroll
        for (int r = 0; r < 4; r++) {
            long grow = mbase + mi * 16 + lg * 4 + r;
            if (grow >= NROWS) continue;
#pragma unroll
            for (int ni = 0; ni < 4; ni++) {
                long gcol = nbase + ni * 16 + lr;
                float v = acc[mi][ni][r];
                long idx = grow * ldc + gcol;
                if (mode == 0)      Qh[idx] = f2h(v);
                else if (mode == 1) Kh[idx] = f2h(v);
                else                HH[idx] = f2h(fmaxf(v, 0.f));
            }
        }
    }
}

// ---------------- fused accumulate GEMM: 6 split-K partials -> fp16 slabs; XCD-swizzled 1D grid 900 ----------------
__global__ __launch_bounds__(256) void gemm_h16_fused(
    const u16* __restrict__ G1, const u16* __restrict__ G2, const u16* __restrict__ HH,
    const u16* __restrict__ WQ, const u16* __restrict__ WK, const u16* __restrict__ XB,
    u16* __restrict__ part) {
    __shared__ __align__(16) u16 As[128 * 32];
    __shared__ __align__(16) u16 Bs[128 * 32];
    int lid = xcd_swz900(blockIdx.x);
    int bx = lid % 6, by = (lid / 6) % 25, zz = lid / 150;
    const u16* A; const u16* B; int lda; int K0;
    if (zz == 0)      { A = G1; B = WQ; lda = 768;  K0 = 0; }
    else if (zz == 1) { A = G2; B = WK; lda = 768;  K0 = 0; }
    else              { A = HH; B = XB; lda = 3072; K0 = (zz - 2) * 768; }
    u16* C = part + (long)zz * SZL;

    int t = threadIdx.x;
    int w = t >> 6, lane = t & 63;
    int lr = lane & 15, lg = lane >> 4;
    int wr = w >> 1, wc = w & 1;
    long row0 = (long)by * 128, col0 = (long)bx * 128;

    f32x4 acc[4][4];
#pragma unroll
    for (int i = 0; i < 4; i++)
#pragma unroll
        for (int j = 0; j < 4; j++) acc[i][j] = (f32x4){0.f, 0.f, 0.f, 0.f};

    int c0 = w * 64 + lane;
    int r0s = c0 >> 2, k0s = (((c0 & 3) ^ ((r0s >> 1) & 3)) << 3);
    int c1 = 256 + w * 64 + lane;
    int r1s = c1 >> 2, k1s = (((c1 & 3) ^ ((r1s >> 1) & 3)) << 3);

    for (int kt = K0; kt < K0 + 768; kt += 32) {
        const u16* AB = A + row0 * lda + kt;
        const u16* BB = B + col0 * (long)lda + kt;
        gld16(AB + (long)r0s * lda + k0s, (char*)As + (w * 64) * 16);
        gld16(AB + (long)r1s * lda + k1s, (char*)As + (256 + w * 64) * 16);
        gld16(BB + (long)r0s * lda + k0s, (char*)Bs + (w * 64) * 16);
        gld16(BB + (long)r1s * lda + k1s, (char*)Bs + (256 + w * 64) * 16);
        __syncthreads();
        f16x8 af[4], bf[4];
#pragma unroll
        for (int mi = 0; mi < 4; mi++) {
            int row = wr * 64 + mi * 16 + lr;
            af[mi] = *(const f16x8*)&As[row * 32 + ((lg ^ ((row >> 1) & 3)) << 3)];
        }
#pragma unroll
        for (int ni = 0; ni < 4; ni++) {
            int row = wc * 64 + ni * 16 + lr;
            bf[ni] = *(const f16x8*)&Bs[row * 32 + ((lg ^ ((row >> 1) & 3)) << 3)];
        }
#pragma unroll
        for (int mi = 0; mi < 4; mi++)
#pragma unroll
            for (int ni = 0; ni < 4; ni++)
                acc[mi][ni] = __builtin_amdgcn_mfma_f32_16x16x32_f16(af[mi], bf[ni], acc[mi][ni], 0, 0, 0);
        __syncthreads();
    }

    long mbase = row0 + wr * 64;
    long nbase = col0 + wc * 64;
#pragma unroll
    for (int mi = 0; mi < 4; mi++) {
#pragma unroll
        for (int r = 0; r < 4; r++) {
            long grow = mbase + mi * 16 + lg * 4 + r;
            if (grow >= NROWS) continue;
#pragma unroll
            for (int ni = 0; ni < 4; ni++) {
                long gcol = nbase + ni * 16 + lr;
                C[grow * D + gcol] = f2h(acc[mi][ni][r]);
            }
        }
    }
}

// ---------------- fused reduce + layernorm: h (+= 6 fp16 slabs) -> LN -> fp16 ----------------
__global__ __launch_bounds__(256) void ln_fuse_kernel(
    float* __restrict__ X, u16* __restrict__ Yh16, const u16* __restrict__ part,
    const float* __restrict__ gamma, const float* __restrict__ beta,
    int compact, int doReduce, int writeBack) {
    int r = blockIdx.x;
    long xrow = compact ? ((long)(r / NPATCH) * NTOK + 1 + (r % NPATCH)) : (long)r;
    float* x = X + xrow * D;
    int t = threadIdx.x;
    float v[3];
    float s = 0.f, ss = 0.f;
#pragma unroll
    for (int i = 0; i < 3; i++) {
        int c = t + 256 * i;
        float val = x[c];
        if (doReduce) {
            long off = xrow * D + c;
            float p01 = h2f(part[off]) + h2f(part[SZL + off]);
            float p23 = h2f(part[2 * SZL + off]) + h2f(part[3 * SZL + off]);
            float p45 = h2f(part[4 * SZL + off]) + h2f(part[5 * SZL + off]);
            val += (p01 + p23) + p45;
            if (writeBack) x[c] = val;
        }
        v[i] = val;
        s += val;
        ss += val * val;
    }
    __shared__ float red[8];
    for (int off = 32; off; off >>= 1) {
        s += __shfl_down(s, off, 64);
        ss += __shfl_down(ss, off, 64);
    }
    int wid = t >> 6, lane = t & 63;
    if (lane == 0) { red[wid] = s; red[4 + wid] = ss; }
    __syncthreads();
    s = red[0] + red[1] + red[2] + red[3];
    ss = red[4] + red[5] + red[6] + red[7];
    float mu = s * (1.f / 768.f);
    float var = ss * (1.f / 768.f) - mu * mu;
    float inv = rsqrtf(var + 1e-5f);
#pragma unroll
    for (int i = 0; i < 3; i++) {
        int c = t + 256 * i;
        float yv = gamma[c] * (v[i] - mu) * inv + beta[c];
        Yh16[(long)r * D + c] = f2h(yv);
    }
}

// ---------------- parallel attention softmax (fp16 Q/K, v_dot2_f32_f16 dots; grid 192x13) ----------------
// Pads: rows 197..207 AND cols 197..207 written as ZERO every step (MFMA downstream requires).
__global__ __launch_bounds__(256) void attn_p_kernel(const u16* __restrict__ Q, const u16* __restrict__ K,
                                                     u16* __restrict__ Pt) {
    __shared__ __align__(16) u16 Ks[NTOK][72];
    int bh = blockIdx.x, mt = blockIdx.y;
    int b = bh / NH, h = bh % NH;
    int t = threadIdx.x;
    const u16* Kb = K + (long)b * NTOK * D + h * HD;
    for (int i = t; i < NTOK * 8; i += 256) {
        int n = i >> 3, c8 = (i & 7) << 3;
        *(uint4*)&Ks[n][c8] = *(const uint4*)(Kb + (long)n * D + c8);
    }
    __syncthreads();
    int ql = t >> 4, l16 = t & 15;
    int m = mt * 16 + ql;
    int mr = m < NTOK ? m : NTOK - 1;
    const u16* Qrow = Q + (long)(b * NTOK + mr) * D + h * HD;
    u16 qb[64];
#pragma unroll
    for (int k = 0; k < 64; k += 8)
        *(f16x8*)&qb[k] = *(const f16x8*)(Qrow + k);
    float s[13];
    float mx = -1e30f;
#pragma unroll
    for (int i = 0; i < 13; i++) {
        int n = i * 16 + l16;
        const u16* kr = Ks[n < NTOK ? n : 0];
        float a0 = 0.f, a1 = 0.f, a2 = 0.f, a3 = 0.f;
#pragma unroll
        for (int k = 0; k < 64; k += 8) {
            f16x8 kv = *(const f16x8*)&kr[k];
            f16x2 k0 = {kv[0], kv[1]}, k1 = {kv[2], kv[3]}, k2 = {kv[4], kv[5]}, k3 = {kv[6], kv[7]};
            a0 = __builtin_amdgcn_fdot2(k0, *(const f16x2*)&qb[k],     a0, false);
            a1 = __builtin_amdgcn_fdot2(k1, *(const f16x2*)&qb[k + 2], a1, false);
            a2 = __builtin_amdgcn_fdot2(k2, *(const f16x2*)&qb[k + 4], a2, false);
            a3 = __builtin_amdgcn_fdot2(k3, *(const f16x2*)&qb[k + 6], a3, false);
        }
        float sv = ((a0 + a1) + (a2 + a3)) * BETA_F;
        s[i] = (n < NTOK) ? sv : -1e30f;
        mx = fmaxf(mx, s[i]);
    }
    mx = fmaxf(mx, __shfl_xor(mx, 1, 64));
    mx = fmaxf(mx, __shfl_xor(mx, 2, 64));
    mx = fmaxf(mx, __shfl_xor(mx, 4, 64));
    mx = fmaxf(mx, __shfl_xor(mx, 8, 64));
    float ssum = 0.f;
#pragma unroll
    for (int i = 0; i < 13; i++) {
        float e = (s[i] > -1e29f) ? __expf(s[i] - mx) : 0.f;
        s[i] = e;
        ssum += e;
    }
    ssum += __shfl_xor(ssum, 1, 64);
    ssum += __shfl_xor(ssum, 2, 64);
    ssum += __shfl_xor(ssum, 4, 64);
    ssum += __shfl_xor(ssum, 8, 64);
    float inv = 1.f / ssum;
    u16* PtB = Pt + (long)bh * PBH;
    if (m < NTOK) {
#pragma unroll
        for (int i = 0; i < 13; i++) {
            int n = i * 16 + l16;
            PtB[(long)m * PLD + n] = (n < NTOK) ? f2h(s[i] * inv) : (u16)0;
        }
    } else {
#pragma unroll
        for (int i = 0; i < 13; i++) {
            int n = i * 16 + l16;
            PtB[(long)m * PLD + n] = 0;
        }
    }
}

// ---------------- attention grads via MFMA: G1 (which=0) + G2 (which=1) ----------------
__global__ __launch_bounds__(256) void attn_g_mfma(
    const u16* __restrict__ Pt, const u16* __restrict__ Qh, const u16* __restrict__ Kh,
    u16* __restrict__ G1, u16* __restrict__ G2) {
    __shared__ __align__(16) u16 Asm[64][224];
    __shared__ __align__(16) u16 Bsm[64][224];
    int z = blockIdx.z;
    int which = z / 192, bh = z - which * 192;
    int b = bh / NH, h = bh % NH;
    int row0 = blockIdx.x * 64;
    const u16* P = Pt + (long)bh * PBH;
    const u16* B = (which ? Qh : Kh) + ((long)b * NTOK) * D + h * HD;
    u16* G = which ? G2 : G1;
    int t = threadIdx.x;

    if (which == 0) {
        for (int idx = t; idx < 64 * 28; idx += 256) {
            int r = idx / 28, c8 = (idx % 28) * 8;
            uint4 v = make_uint4(0, 0, 0, 0);
            if (row0 + r < PROWS && c8 < PLD)
                v = *(const uint4*)(P + (long)(row0 + r) * PLD + c8);
            *(uint4*)&Asm[r][c8] = v;
        }
    } else {
        for (int idx = t; idx < 224 * 8; idx += 256) {
            int m = idx / 8, j8 = (idx % 8) * 8;
            u16 vals[8];
            if (m < PROWS && row0 + j8 < PLD) {
                *(uint4*)vals = *(const uint4*)(P + (long)m * PLD + row0 + j8);
            } else {
#pragma unroll
                for (int j = 0; j < 8; j++) vals[j] = 0;
            }
#pragma unroll
            for (int j = 0; j < 8; j++) Asm[j8 + j][m] = vals[j];
        }
    }
    for (int idx = t; idx < 224 * 8; idx += 256) {
        int n = idx / 8, c8 = (idx % 8) * 8;
        u16 vals[8];
        if (n < PROWS) {
            *(uint4*)vals = *(const uint4*)(B + (long)n * D + c8);
        } else {
#pragma unroll
            for (int j = 0; j < 8; j++) vals[j] = 0;
        }
#pragma unroll
        for (int j = 0; j < 8; j++) Bsm[c8 + j][n] = vals[j];
    }
    __syncthreads();

    int w = t >> 6, lane = t & 63;
    int lr = lane & 15, lg = lane >> 4;
    f32x4 acc[4];
#pragma unroll
    for (int i = 0; i < 4; i++) acc[i] = (f32x4){0.f, 0.f, 0.f, 0.f};
#pragma unroll
    for (int kt = 0; kt < 224; kt += 32) {
        f16x8 a = *(const f16x8*)&Asm[w * 16 + lr][kt + lg * 8];
#pragma unroll
        for (int ni = 0; ni < 4; ni++) {
            f16x8 bfr = *(const f16x8*)&Bsm[ni * 16 + lr][kt + lg * 8];
            acc[ni] = __builtin_amdgcn_mfma_f32_16x16x32_f16(a, bfr, acc[ni], 0, 0, 0);
        }
    }

#pragma unroll
    for (int ni = 0; ni < 4; ni++) {
#pragma unroll
        for (int r = 0; r < 4; r++) {
            int m = row0 + w * 16 + lg * 4 + r;
            if (m < NTOK) {
                int c = ni * 16 + lr;
                G[((long)(b * NTOK + m)) * D + h * HD + c] = f2h(acc[ni][r]);
            }
        }
    }
}

// ================= setup pieces =================

__global__ __launch_bounds__(256) void patchify_kernel(const float* __restrict__ x, u16* __restrict__ tok) {
    int idx = blockIdx.x * 256 + threadIdx.x;
    const int total = NB * NPATCH * D;
    if (idx >= total) return;
    int d = idx % D;
    int p = (idx / D) % NPATCH;
    int b = idx / (D * NPATCH);
    int c = d >> 8;
    int pi = (d >> 4) & 15;
    int pj = d & 15;
    int hp = p / 14, wp = p % 14;
    int row = hp * 16 + pi, col = wp * 16 + pj;
    tok[idx] = f2h(x[(((long)b * 3 + c) * 224 + row) * 224 + col]);
}

__global__ __launch_bounds__(256) void cls_pos_kernel(float* __restrict__ h, const float* __restrict__ cls,
                                                      const float* __restrict__ pos) {
    int idx = blockIdx.x * 256 + threadIdx.x;
    const int total = NB * NTOK * D;
    if (idx >= total) return;
    int d = idx % D;
    int n = (idx / D) % NTOK;
    float v = pos[n * D + d];
    if (n == 0) h[idx] = cls[d] + v;
    else        h[idx] = h[idx] + v;
}

__global__ __launch_bounds__(256) void wcat_kernel(const float* __restrict__ w, float* __restrict__ Wm) {
    int idx = blockIdx.x * 256 + threadIdx.x;
    const int total = NH * D * HD;
    if (idx >= total) return;
    int k = idx & 63;
    int d = (idx >> 6) % D;
    int hh = idx / (D * HD);
    Wm[d * D + hh * HD + k] = w[idx];
}

// ---------------- COALESCED tiled transpose prep: dst[c][r] = f2h(src[r][c]) ----------------
__global__ __launch_bounds__(256) void prep_transpose_h(const float* __restrict__ src,
                                                        u16* __restrict__ dst, int R, int C) {
    __shared__ float tile[32][33];
    int c0 = blockIdx.x * 32, r0 = blockIdx.y * 32;
    int tx = threadIdx.x & 31, ty = threadIdx.x >> 5;
    for (int i = ty; i < 32; i += 8)
        tile[i][tx] = src[(long)(r0 + i) * C + c0 + tx];
    __syncthreads();
    for (int i = ty; i < 32; i += 8)
        dst[(long)(c0 + i) * R + r0 + tx] = f2h(tile[tx][i]);
}
__global__ __launch_bounds__(256) void prep_convert_h(const float* __restrict__ src,
                                                      u16* __restrict__ dst, int n) {
    int idx = blockIdx.x * 256 + threadIdx.x;
    if (idx >= n) return;
    dst[idx] = f2h(src[idx]);
}

extern "C" void kernel_launch(void* const* d_in, const int* in_sizes, int n_in,
                              void* d_out, int out_size, void* d_ws, size_t ws_size,
                              hipStream_t stream) {
    const float* x        = (const float*)d_in[0];
    const float* patch_w  = (const float*)d_in[1];
    const float* patch_b  = (const float*)d_in[2];
    const float* cls_tok  = (const float*)d_in[3];
    const float* pos_emb  = (const float*)d_in[4];
    const float* ln_gamma = (const float*)d_in[5];
    const float* ln_beta  = (const float*)d_in[6];
    const float* wq       = (const float*)d_in[7];
    const float* wk       = (const float*)d_in[8];
    const float* xi       = (const float*)d_in[9];
    const float* out_gamma= (const float*)d_in[10];
    const float* out_beta = (const float*)d_in[11];
    const float* out_w    = (const float*)d_in[12];
    const float* out_b    = (const float*)d_in[13];
    float* out = (float*)d_out;

    float* ws = (float*)d_ws;
    const long SZ = SZL;
    const long AR = (long)AROWS * D;
    float* h  = ws;
    u16* gh16    = (u16*)(ws + SZ);
    u16* Qh16    = gh16 + AR;
    u16* Kh16    = Qh16 + AR;
    u16* WmQTh16 = Kh16 + AR;
    u16* WmKTh16 = WmQTh16 + DD;
    u16* WmQh16  = WmKTh16 + DD;
    u16* WmKh16  = WmQh16 + DD;
    u16* xiTh16  = WmKh16 + DD;
    u16* xibh16  = xiTh16 + DH;
    u16* G1h16   = xibh16 + DH;
    u16* G2h16   = G1h16 + AR;
    u16* HH16    = G2h16 + AR;
    u16* owTh16  = HH16 + (long)AROWS * HOP;
    u16* pwTh16  = owTh16 + DD;
    // shared region (sequenced aliasing): part (6*SZ u16) | Pt (192*PBH u16) | tok16 (setup)
    char* R1c = (char*)(pwTh16 + DD);
    u16* Pt16   = (u16*)R1c;
    u16* part16 = (u16*)R1c;
    u16* tok16  = (u16*)R1c;
    float* WmQ  = (float*)(R1c + (size_t)6 * SZ * 2);   // setup-only f32 scratch
    float* WmK  = WmQ + DD;

    // ---- setup ----
    patchify_kernel<<<(NB * NPATCH * D + 255) / 256, 256, 0, stream>>>(x, tok16);
    wcat_kernel<<<(NH * D * HD + 255) / 256, 256, 0, stream>>>(wq, WmQ);
    wcat_kernel<<<(NH * D * HD + 255) / 256, 256, 0, stream>>>(wk, WmK);
    prep_transpose_h<<<dim3(24, 24), 256, 0, stream>>>(WmQ, WmQTh16, 768, 768);
    prep_transpose_h<<<dim3(24, 24), 256, 0, stream>>>(WmK, WmKTh16, 768, 768);
    prep_convert_h<<<(DD + 255) / 256, 256, 0, stream>>>(WmQ, WmQh16, DD);
    prep_convert_h<<<(DD + 255) / 256, 256, 0, stream>>>(WmK, WmKh16, DD);
    prep_transpose_h<<<dim3(96, 24), 256, 0, stream>>>(xi, xiTh16, 768, HOP);
    prep_convert_h<<<(DH + 255) / 256, 256, 0, stream>>>(xi, xibh16, DH);
    prep_transpose_h<<<dim3(24, 24), 256, 0, stream>>>(out_w, owTh16, 768, 768);
    prep_transpose_h<<<dim3(24, 24), 256, 0, stream>>>(patch_w, pwTh16, 768, 768);
    // patch embed via fp16 MFMA: h rows 1..196 per batch (f32 out + f32 bias)
    gemm_h16<<<dim3(6, 2, NB), 256, 0, stream>>>(
        tok16, pwTh16, h + D, patch_b,
        NPATCH, D, D, D, D, D, 0,
        (long)NPATCH * D, 0, (long)NTOK * D);
    cls_pos_kernel<<<(NB * NTOK * D + 255) / 256, 256, 0, stream>>>(h, cls_tok, pos_emb);

    for (int step = 0; step < TSTEPS; step++) {
        ln_fuse_kernel<<<NROWS, 256, 0, stream>>>(h, gh16, part16, ln_gamma, ln_beta,
                                                  0, step > 0 ? 1 : 0, 1);
        fused_proj<<<900, 256, 0, stream>>>(gh16, WmQTh16, WmKTh16, xiTh16, Qh16, Kh16, HH16);
        attn_p_kernel<<<dim3(192, 13), 256, 0, stream>>>(Qh16, Kh16, Pt16);
        attn_g_mfma<<<dim3(4, 1, 384), 256, 0, stream>>>(Pt16, Qh16, Kh16, G1h16, G2h16);
        gemm_h16_fused<<<900, 256, 0, stream>>>(
            G1h16, G2h16, HH16, WmQh16, WmKh16, xibh16, part16);
    }

    // ---- final: reduce + LN (compact) -> fp16, then out projection (fp16 MFMA) ----
    ln_fuse_kernel<<<NPROWS, 256, 0, stream>>>(h, gh16, part16, out_gamma, out_beta, 1, 1, 0);
    gemm_h16<<<dim3(6, 25, 1), 256, 0, stream>>>(
        gh16, owTh16, out, out_b, NPROWS, D, D, D, D, D, 0, 0, 0, 0);
}